// Round 16
// baseline (3223.100 us; speedup 1.0000x reference)
//
#include <hip/hip_runtime.h>
#include <math.h>

typedef unsigned short u16;
typedef __attribute__((ext_vector_type(8))) short short8v;   // 8 x bf16
typedef __attribute__((ext_vector_type(4))) float f32x4;

__device__ __forceinline__ float geluf(float x) {
    return 0.5f * x * (1.0f + erff(x * 0.70710678118654752f));
}
__device__ __forceinline__ float bf2f(u16 u) { return __uint_as_float((unsigned)u << 16); }
__device__ __forceinline__ u16 f2bf(float f) {
    unsigned x = __float_as_uint(f);
    unsigned r = x + 0x7FFFu + ((x >> 16) & 1u);
    return (u16)(r >> 16);
}
// fast tanh via exp2-based __expf; err ~1e-6 << bf16 ulp
__device__ __forceinline__ float tanhfast(float x) {
    float cx = fminf(fmaxf(x, -15.f), 15.f);
    float t = __expf(2.f * cx);
    return (t - 1.f) / (t + 1.f);
}
// async 16B global->LDS (direct, no VGPR round-trip). lds base wave-uniform; HW adds lane*16.
__device__ __forceinline__ void gll16(const short* g, short* l) {
    __builtin_amdgcn_global_load_lds(
        (const __attribute__((address_space(1))) void*)g,
        (__attribute__((address_space(3))) void*)l, 16, 0, 0);
}

template<bool BF>
__device__ __forceinline__ float4 ld4(const void* base, long long elemOff) {
    if (BF) {
        ushort4 u = *(const ushort4*)((const u16*)base + elemOff);
        return make_float4(bf2f(u.x), bf2f(u.y), bf2f(u.z), bf2f(u.w));
    } else {
        return *(const float4*)((const float*)base + elemOff);
    }
}

// ================= CSR build =================
__global__ __launch_bounds__(256) void cnt_kernel(const int* __restrict__ dst, int* __restrict__ cnt, int E, int Nn) {
    int e = blockIdx.x * 256 + threadIdx.x;
    if (e < E) {
        int d = dst[e];
        if ((unsigned)d < (unsigned)Nn) atomicAdd(&cnt[d], 1);
    }
}
__global__ __launch_bounds__(256) void scan1_kernel(const int* __restrict__ cnt, int* __restrict__ rp,
                                                    int* __restrict__ bs, int n) {
    __shared__ int sh[256];
    int i = blockIdx.x * 256 + threadIdx.x;
    int v = (i < n) ? cnt[i] : 0;
    sh[threadIdx.x] = v; __syncthreads();
    for (int o = 1; o < 256; o <<= 1) {
        int t = (threadIdx.x >= o) ? sh[threadIdx.x - o] : 0;
        __syncthreads();
        sh[threadIdx.x] += t;
        __syncthreads();
    }
    if (i < n) rp[i] = sh[threadIdx.x] - v;
    if (threadIdx.x == 255) bs[blockIdx.x] = sh[255];
}
__global__ __launch_bounds__(1024) void scan2_kernel(int* __restrict__ bs, int nb) {
    __shared__ int sh[1024];
    int v = (threadIdx.x < nb) ? bs[threadIdx.x] : 0;
    sh[threadIdx.x] = v; __syncthreads();
    for (int o = 1; o < 1024; o <<= 1) {
        int t = (threadIdx.x >= o) ? sh[threadIdx.x - o] : 0;
        __syncthreads();
        sh[threadIdx.x] += t;
        __syncthreads();
    }
    if (threadIdx.x < nb) bs[threadIdx.x] = sh[threadIdx.x] - v;
}
__global__ __launch_bounds__(256) void scan3_kernel(int* __restrict__ rp, int* __restrict__ cur,
                                                    const int* __restrict__ bs, int n, int E) {
    int i = blockIdx.x * 256 + threadIdx.x;
    if (i < n) {
        int v = rp[i] + bs[blockIdx.x];
        rp[i] = v;
        cur[i] = v;
    }
    if (i == 0) rp[n] = E;
}
__global__ __launch_bounds__(256) void fill_kernel(const int* __restrict__ src, const int* __restrict__ dst,
                                                   int* __restrict__ cur, int* __restrict__ srcs, int E, int Nn) {
    int e = blockIdx.x * 256 + threadIdx.x;
    if (e >= E) return;
    int d = dst[e];
    if ((unsigned)d >= (unsigned)Nn) return;
    int s = src[e];
    if ((unsigned)s >= (unsigned)Nn) s = 0;
    int p = atomicAdd(&cur[d], 1);
    srcs[p] = s;
}

// ================= CSR mean-aggregation -> bf16 m (4-way ILP) =================
template<bool L0>
__global__ __launch_bounds__(256) void agg_csr_kernel(const void* __restrict__ X, int ldx,
    const int* __restrict__ rp, const int* __restrict__ srcs,
    u16* __restrict__ m, int c0, int rows)
{
    int lrow = blockIdx.x * 4 + (threadIdx.x >> 6);
    if (lrow >= rows) return;
    int lane = threadIdx.x & 63;
    int r = c0 + lrow;
    int b = rp[r], e = rp[r + 1];
    float inv = 1.0f / fmaxf((float)(e - b), 1.0f);
    if (L0) {
        float a0 = 0.f, a1 = 0.f, b0 = 0.f, b1 = 0.f;
        float c0a = 0.f, c1a = 0.f, d0 = 0.f, d1 = 0.f;
        int i = b;
        for (; i + 4 <= e; i += 4) {
            int s0 = srcs[i], s1 = srcs[i + 1], s2 = srcs[i + 2], s3 = srcs[i + 3];
            float2 v0 = *(const float2*)((const float*)X + (long long)s0 * ldx + lane * 2);
            float2 v1 = *(const float2*)((const float*)X + (long long)s1 * ldx + lane * 2);
            float2 v2 = *(const float2*)((const float*)X + (long long)s2 * ldx + lane * 2);
            float2 v3 = *(const float2*)((const float*)X + (long long)s3 * ldx + lane * 2);
            a0 += v0.x; a1 += v0.y;
            b0 += v1.x; b1 += v1.y;
            c0a += v2.x; c1a += v2.y;
            d0 += v3.x; d1 += v3.y;
        }
        for (; i < e; ++i) {
            int s0 = srcs[i];
            float2 v0 = *(const float2*)((const float*)X + (long long)s0 * ldx + lane * 2);
            a0 += v0.x; a1 += v0.y;
        }
        a0 += b0 + c0a + d0; a1 += b1 + c1a + d1;
        ushort2 o; o.x = f2bf(a0 * inv); o.y = f2bf(a1 * inv);
        *(ushort2*)(m + (long long)lrow * 128 + lane * 2) = o;
    } else {
        float a0 = 0.f, a1 = 0.f, a2 = 0.f, a3 = 0.f;
        float b0 = 0.f, b1 = 0.f, b2 = 0.f, b3 = 0.f;
        float c0_ = 0.f, c1_ = 0.f, c2_ = 0.f, c3_ = 0.f;
        float d0 = 0.f, d1 = 0.f, d2 = 0.f, d3 = 0.f;
        int i = b;
        for (; i + 4 <= e; i += 4) {
            int s0 = srcs[i], s1 = srcs[i + 1], s2 = srcs[i + 2], s3 = srcs[i + 3];
            ushort4 u0 = *(const ushort4*)((const u16*)X + (long long)s0 * ldx + lane * 4);
            ushort4 u1 = *(const ushort4*)((const u16*)X + (long long)s1 * ldx + lane * 4);
            ushort4 u2 = *(const ushort4*)((const u16*)X + (long long)s2 * ldx + lane * 4);
            ushort4 u3 = *(const ushort4*)((const u16*)X + (long long)s3 * ldx + lane * 4);
            a0 += bf2f(u0.x); a1 += bf2f(u0.y); a2 += bf2f(u0.z); a3 += bf2f(u0.w);
            b0 += bf2f(u1.x); b1 += bf2f(u1.y); b2 += bf2f(u1.z); b3 += bf2f(u1.w);
            c0_ += bf2f(u2.x); c1_ += bf2f(u2.y); c2_ += bf2f(u2.z); c3_ += bf2f(u2.w);
            d0 += bf2f(u3.x); d1 += bf2f(u3.y); d2 += bf2f(u3.z); d3 += bf2f(u3.w);
        }
        for (; i < e; ++i) {
            int s0 = srcs[i];
            ushort4 u0 = *(const ushort4*)((const u16*)X + (long long)s0 * ldx + lane * 4);
            a0 += bf2f(u0.x); a1 += bf2f(u0.y); a2 += bf2f(u0.z); a3 += bf2f(u0.w);
        }
        a0 += b0 + c0_ + d0; a1 += b1 + c1_ + d1;
        a2 += b2 + c2_ + d2; a3 += b3 + c3_ + d3;
        ushort4 o;
        o.x = f2bf(a0 * inv); o.y = f2bf(a1 * inv); o.z = f2bf(a2 * inv); o.w = f2bf(a3 * inv);
        *(ushort4*)(m + (long long)lrow * 256 + lane * 4) = o;
    }
}

// ================= merged weight prep =================
struct PrepArgs {
    const float* W[11];
    short* outp[11];
    int K[11], Nc[11], kOff[11], Ktot[11];
    int start[12];
};
__global__ __launch_bounds__(256) void prep_all_kernel(PrepArgs a) {
    int idx = blockIdx.x * 256 + threadIdx.x;
    if (idx >= a.start[11]) return;
    int si = 0;
    #pragma unroll
    for (int j = 1; j < 11; ++j) si += (idx >= a.start[j]);
    int local = idx - a.start[si];
    int Nc = a.Nc[si];
    int k = local / Nc, n = local % Nc;
    a.outp[si][(long long)n * a.Ktot[si] + a.kOff[si] + k] = (short)f2bf(a.W[si][local]);
}

// ---------------- fp32 staging helper (reg path) ----------------
__device__ __forceinline__ void loadrow32(const float* p, short8v& o0, short8v& o1) {
    float4 a = *(const float4*)p;
    float4 b = *(const float4*)(p + 4);
    float4 c = *(const float4*)(p + 8);
    float4 d = *(const float4*)(p + 12);
    short8v r0, r1;
    r0[0] = (short)f2bf(a.x); r0[1] = (short)f2bf(a.y); r0[2] = (short)f2bf(a.z); r0[3] = (short)f2bf(a.w);
    r0[4] = (short)f2bf(b.x); r0[5] = (short)f2bf(b.y); r0[6] = (short)f2bf(b.z); r0[7] = (short)f2bf(b.w);
    r1[0] = (short)f2bf(c.x); r1[1] = (short)f2bf(c.y); r1[2] = (short)f2bf(c.z); r1[3] = (short)f2bf(c.w);
    r1[4] = (short)f2bf(d.x); r1[5] = (short)f2bf(d.y); r1[6] = (short)f2bf(d.z); r1[7] = (short)f2bf(d.w);
    o0 = r0; o1 = r1;
}

// ================= MFMA GEMM v3: async staging + chunk-XOR bank swizzle =================
template<int EPI, bool A1BF, bool A2BF, bool CBF, bool STAT, bool NORM>
__global__ __launch_bounds__(256) void mm_kernel(
    const void* __restrict__ A1, int lda1,
    const void* __restrict__ A2, int lda2,
    int K1, int K2,
    const short* __restrict__ Bhi, int ldb,
    const float* __restrict__ bias,
    const float* __restrict__ resid, int ldres,
    float* __restrict__ s1, float* __restrict__ s2,
    void* __restrict__ C, int ldc, int M)
{
    __shared__ short AsL[4096];      // [128][32] linear, chunk-swizzled content
    __shared__ short BhL[4096];
    __shared__ float cst[256];       // STAT: colsum[128] | colsq[128]
    __shared__ float rsq[128][2];    // NORM
    const int t = threadIdx.x;
    const int rowbase = blockIdx.y * 128;
    const int colbase = blockIdx.x * 128;
    const int lane = t & 63;
    const int wv = t >> 6;
    const int wr = (wv >> 1) << 6;
    const int wc = (wv & 1) << 6;
    const int l15 = lane & 15;
    const int rgrp = (lane >> 4) << 2;
    const int lr16 = lane >> 2;            // 0..15
    const int swz = (((lane & 3) ^ (lr16 & 3)) << 3);   // swizzled global elem offset
    const int ldsW = wv * 512;             // wave-uniform LDS elem base
    const int rdk = (((lane >> 4) ^ (l15 & 3)) << 3);   // read-side swizzled k offset
    if (STAT && t < 256) cst[t] = 0.f;
    f32x4 acc[4][4] = {};
    const int k1t = K1 >> 5;
    const int KT = (K1 + K2) >> 5;

    for (int kt = 0; kt < KT; ++kt) {
        const bool p1 = kt < k1t;
        const int kbl = (p1 ? kt : kt - k1t) << 5;
        {
            long long kb = (long long)(kt << 5) + swz;
            int r0 = colbase + wv * 16 + lr16;
            gll16(Bhi + (long long)r0 * ldb + kb, BhL + ldsW);
            gll16(Bhi + (long long)(r0 + 64) * ldb + kb, BhL + 2048 + ldsW);
        }
        if (p1 ? A1BF : A2BF) {
            const short* Ab = (const short*)(p1 ? A1 : A2);
            const int lda = p1 ? lda1 : lda2;
            int r0 = rowbase + wv * 16 + lr16;      if (r0 >= M) r0 = M - 1;
            int r1 = rowbase + 64 + wv * 16 + lr16; if (r1 >= M) r1 = M - 1;
            gll16(Ab + (long long)r0 * lda + kbl + swz, AsL + ldsW);
            gll16(Ab + (long long)r1 * lda + kbl + swz, AsL + 2048 + ldsW);
        } else {
            const float* Ab = (const float*)(p1 ? A1 : A2);
            const int lda = p1 ? lda1 : lda2;
            int row = t >> 1, h = (t & 1) << 1;
            int r = rowbase + row;
            short8v o0 = {0,0,0,0,0,0,0,0}, o1 = {0,0,0,0,0,0,0,0};
            if (r < M) loadrow32(Ab + (long long)r * lda + kbl + (h << 3), o0, o1);
            *(short8v*)&AsL[row * 32 + ((h ^ (row & 3)) << 3)]       = o0;
            *(short8v*)&AsL[row * 32 + (((h + 1) ^ (row & 3)) << 3)] = o1;
        }
        __syncthreads();
        short8v a4[4], b4[4];
        #pragma unroll
        for (int mr = 0; mr < 4; ++mr)
            a4[mr] = *(short8v*)&AsL[(wr + mr * 16 + l15) * 32 + rdk];
        #pragma unroll
        for (int nr = 0; nr < 4; ++nr)
            b4[nr] = *(short8v*)&BhL[(wc + nr * 16 + l15) * 32 + rdk];
        #pragma unroll
        for (int mr = 0; mr < 4; ++mr)
            #pragma unroll
            for (int nr = 0; nr < 4; ++nr)
                acc[mr][nr] = __builtin_amdgcn_mfma_f32_16x16x32_bf16(a4[mr], b4[nr], acc[mr][nr], 0, 0, 0);
        __syncthreads();
    }

    if (NORM) {
        float rs[4][4] = {};
        #pragma unroll
        for (int nr = 0; nr < 4; ++nr) {
            int c = colbase + wc + nr * 16 + l15;
            float bi = bias[c];
            #pragma unroll
            for (int mr = 0; mr < 4; ++mr)
                #pragma unroll
                for (int i = 0; i < 4; ++i) {
                    int r = rowbase + wr + mr * 16 + rgrp + i;
                    float v = 0.f;
                    if (r < M) {
                        v = acc[mr][nr][i] + bi;
                        if (EPI == 3) v += resid[(long long)r * ldres + c];
                        if (EPI == 1) v = geluf(v);
                    }
                    acc[mr][nr][i] = v;
                    rs[mr][i] += v * v;
                }
        }
        #pragma unroll
        for (int mr = 0; mr < 4; ++mr)
            #pragma unroll
            for (int i = 0; i < 4; ++i) {
                float s = rs[mr][i];
                s += __shfl_xor(s, 1); s += __shfl_xor(s, 2);
                s += __shfl_xor(s, 4); s += __shfl_xor(s, 8);
                rs[mr][i] = s;
            }
        if (l15 == 0) {
            #pragma unroll
            for (int mr = 0; mr < 4; ++mr)
                #pragma unroll
                for (int i = 0; i < 4; ++i)
                    rsq[wr + mr * 16 + rgrp + i][wv & 1] = rs[mr][i];
        }
        __syncthreads();
        #pragma unroll
        for (int mr = 0; mr < 4; ++mr)
            #pragma unroll
            for (int i = 0; i < 4; ++i) {
                int rl = wr + mr * 16 + rgrp + i;
                int r = rowbase + rl;
                if (r >= M) continue;
                float inv = 1.0f / (sqrtf(rsq[rl][0] + rsq[rl][1]) + 1e-10f);
                #pragma unroll
                for (int nr = 0; nr < 4; ++nr) {
                    int c = colbase + wc + nr * 16 + l15;
                    float v = acc[mr][nr][i] * inv;
                    if (CBF) ((u16*)C)[(long long)r * ldc + c] = f2bf(v);
                    else     ((float*)C)[(long long)r * ldc + c] = v;
                }
            }
    } else {
        #pragma unroll
        for (int nr = 0; nr < 4; ++nr) {
            int c = colbase + wc + nr * 16 + l15;
            float bi = bias[c];
            float cp = 0.f, cq = 0.f;
            #pragma unroll
            for (int mr = 0; mr < 4; ++mr)
                #pragma unroll
                for (int i = 0; i < 4; ++i) {
                    int r = rowbase + wr + mr * 16 + rgrp + i;
                    if (r >= M) continue;
                    float v = acc[mr][nr][i] + bi;
                    if (EPI == 1) v = geluf(v);
                    if (EPI == 3) v += resid[(long long)r * ldres + c];
                    if (CBF) ((u16*)C)[(long long)r * ldc + c] = f2bf(v);
                    else     ((float*)C)[(long long)r * ldc + c] = v;
                    if (STAT) { cp += v; cq += v * v; }
                }
            if (STAT) {
                cp += __shfl_xor(cp, 16); cp += __shfl_xor(cp, 32);
                cq += __shfl_xor(cq, 16); cq += __shfl_xor(cq, 32);
                if (lane < 16) {
                    int cl = wc + nr * 16 + l15;
                    atomicAdd(&cst[cl], cp);
                    atomicAdd(&cst[128 + cl], cq);
                }
            }
        }
        if (STAT) {
            __syncthreads();
            if (t < 128) {
                atomicAdd(s1 + colbase + t, cst[t]);
                atomicAdd(s2 + colbase + t, cst[128 + t]);
            }
        }
    }
}

// ================= pair kernel v8: 128 pairs/block, 8 waves (512 threads) =================
// Same per-wave register shape as v6 (acc[2][4], az[16]); 4 row-groups x 2 col-groups.
// LDS ~68.6 KB -> 2 blocks/CU = 16 waves (vs ~7 at 256-thread blocks).
__global__ __launch_bounds__(512) void pair_kernel(
    const u16* __restrict__ zf,
    const int* __restrict__ g1, const int* __restrict__ g2,
    int Nn, int P,
    const short* __restrict__ C1t, const float* __restrict__ c1,
    const short* __restrict__ C2t, const float* __restrict__ c2,
    const float* __restrict__ C3, const float* __restrict__ c3,
    float* __restrict__ out)
{
    __shared__ short E1s[128 * 264];
    __shared__ float sc[128][2];
    const int t = threadIdx.x;
    const int lane = t & 63;
    const int wv = t >> 6;            // 0..7
    const int wr = (wv >> 1) << 5;    // 0,32,64,96
    const int wc = (wv & 1) << 6;     // 0,64
    const int l15 = lane & 15;
    const int kreg = (lane >> 4) << 3;
    const int rgrp = (lane >> 4) << 2;
    const int p0 = blockIdx.x * 128;

    int gidx[2][2];
    #pragma unroll
    for (int mr = 0; mr < 2; ++mr) {
        int pr = p0 + wr + mr * 16 + l15;
        int a = (pr < P) ? g1[pr] : 0;  if ((unsigned)a >= (unsigned)Nn) a = 0;
        gidx[0][mr] = a;
        int b = (pr < P) ? g2[pr] : 0;  if ((unsigned)b >= (unsigned)Nn) b = 0;
        gidx[1][mr] = b;
    }

    // hoist: all 16 zf A-fragments loaded once (z[g1]|z[g2], full K=256)
    short8v az[2][2][4];   // [half][mr][ktl]
    #pragma unroll
    for (int half = 0; half < 2; ++half)
        #pragma unroll
        for (int mr = 0; mr < 2; ++mr)
            #pragma unroll
            for (int ktl = 0; ktl < 4; ++ktl)
                az[half][mr][ktl] = *(const short8v*)((const short*)zf
                    + (long long)gidx[half][mr] * 128 + (ktl << 5) + kreg);

    // ---- e1: [128 pairs] x [256 cols], K = 256; barrier-free, A from registers ----
    #pragma unroll
    for (int ch = 0; ch < 2; ++ch) {
        f32x4 acc1[2][4] = {};
        #pragma unroll
        for (int kt = 0; kt < 8; ++kt) {
            const int half = kt >> 2;
            const int ktl = kt & 3;
            short8v b4[4];
            #pragma unroll
            for (int nr = 0; nr < 4; ++nr)
                b4[nr] = *(const short8v*)(C1t + (long long)(ch * 128 + wc + nr * 16 + l15) * 256 + (kt << 5) + kreg);
            #pragma unroll
            for (int mr = 0; mr < 2; ++mr)
                #pragma unroll
                for (int nr = 0; nr < 4; ++nr)
                    acc1[mr][nr] = __builtin_amdgcn_mfma_f32_16x16x32_bf16(az[half][mr][ktl], b4[nr], acc1[mr][nr], 0, 0, 0);
        }
        // gelu + bf16 -> E1s (disjoint 32-row x 64-col region per wave per ch)
        #pragma unroll
        for (int nr = 0; nr < 4; ++nr) {
            int cc = wc + nr * 16 + l15;
            float bi = c1[ch * 128 + cc];
            #pragma unroll
            for (int mr = 0; mr < 2; ++mr)
                #pragma unroll
                for (int i = 0; i < 4; ++i) {
                    float v = geluf(acc1[mr][nr][i] + bi);
                    E1s[(wr + mr * 16 + rgrp + i) * 264 + ch * 128 + cc] = (short)f2bf(v);
                }
        }
    }
    __syncthreads();

    // ---- e2: [128] x [128], K = 256 from E1s; B direct from L2-resident C2t ----
    f32x4 acc[2][4] = {};
    #pragma unroll
    for (int kt = 0; kt < 8; ++kt) {
        short8v a4[2], b4[4];
        #pragma unroll
        for (int mr = 0; mr < 2; ++mr)
            a4[mr] = *(short8v*)&E1s[(wr + mr * 16 + l15) * 264 + (kt << 5) + kreg];
        #pragma unroll
        for (int nr = 0; nr < 4; ++nr)
            b4[nr] = *(const short8v*)(C2t + (long long)(wc + nr * 16 + l15) * 256 + (kt << 5) + kreg);
        #pragma unroll
        for (int mr = 0; mr < 2; ++mr)
            #pragma unroll
            for (int nr = 0; nr < 4; ++nr)
                acc[mr][nr] = __builtin_amdgcn_mfma_f32_16x16x32_bf16(a4[mr], b4[nr], acc[mr][nr], 0, 0, 0);
    }

    // ---- score: gelu(e2 + c2) . C3, row-reduce, sigmoid ----
    float pr_[2][4] = {};
    #pragma unroll
    for (int nr = 0; nr < 4; ++nr) {
        int cc = wc + nr * 16 + l15;
        float bi = c2[cc];
        float w3 = C3[cc];
        #pragma unroll
        for (int mr = 0; mr < 2; ++mr)
            #pragma unroll
            for (int i = 0; i < 4; ++i)
                pr_[mr][i] += geluf(acc[mr][nr][i] + bi) * w3;
    }
    #pragma unroll
    for (int mr = 0; mr < 2; ++mr)
        #pragma unroll
        for (int i = 0; i < 4; ++i) {
            float s = pr_[mr][i];
            s += __shfl_xor(s, 1); s += __shfl_xor(s, 2);
            s += __shfl_xor(s, 4); s += __shfl_xor(s, 8);
            pr_[mr][i] = s;
        }
    if (l15 == 0) {
        #pragma unroll
        for (int mr = 0; mr < 2; ++mr)
            #pragma unroll
            for (int i = 0; i < 4; ++i)
                sc[wr + mr * 16 + rgrp + i][wv & 1] = pr_[mr][i];
    }
    __syncthreads();
    if (t < 128) {
        int p = p0 + t;
        if (p < P) {
            float x = sc[t][0] + sc[t][1] + c3[0];
            out[p] = 1.0f / (1.0f + expf(-x));
        }
    }
}

// ---------------- GraphNorm apply (+res, + optional fused DyT), bf16 in place ----------------
template<bool DYT>
__global__ __launch_bounds__(256) void gn_apply_kernel(u16* __restrict__ G, int ldg,
    const u16* __restrict__ prev, int ldp, int M,
    const float* __restrict__ s1, const float* __restrict__ s2,
    const float* __restrict__ gw, const float* __restrict__ gb, const float* __restrict__ gs,
    float invN,
    const float* __restrict__ dA, const float* __restrict__ dW, const float* __restrict__ dB)
{
    long long idx = (long long)blockIdx.x * blockDim.x + threadIdx.x;
    if (idx >= (long long)M * 64) return;
    int c0 = (int)(idx & 63) << 2;
    long long r = idx >> 6;
    float4 g = ld4<true>(G, r * ldg + c0);
    float o[4] = {g.x, g.y, g.z, g.w};
    float alpha = DYT ? dA[0] : 0.f;
    #pragma unroll
    for (int j = 0; j < 4; ++j) {
        int c = c0 + j;
        float mu = s1[c] * invN;
        float ms = gs[c];
        float var = s2[c] * invN - mu * mu * ms * (2.0f - ms);
        float rstd = rsqrtf(var + 1e-5f);
        o[j] = (o[j] - ms * mu) * rstd * gw[c] + gb[c];
    }
    if (prev) {
        float4 pv = ld4<true>(prev, r * ldp + c0);
        o[0] += pv.x; o[1] += pv.y; o[2] += pv.z; o[3] += pv.w;
    }
    if (DYT) {
        #pragma unroll
        for (int j = 0; j < 4; ++j)
            o[j] = tanhfast(alpha * o[j]) * dW[c0 + j] + dB[c0 + j];
    }
    ushort4 u; u.x = f2bf(o[0]); u.y = f2bf(o[1]); u.z = f2bf(o[2]); u.w = f2bf(o[3]);
    *(ushort4*)((u16*)G + r * ldg + c0) = u;
}

// ---------------- DynamicTanh on cols 0..511 of Z[N,768] ----------------
__global__ __launch_bounds__(256) void dyt512_kernel(u16* __restrict__ Z,
    const float* __restrict__ alphaP, const float* __restrict__ w, const float* __restrict__ b,
    long long total)   // rows * 64
{
    long long idx = (long long)blockIdx.x * blockDim.x + threadIdx.x;
    if (idx >= total) return;
    int c0 = (int)(idx & 63) << 3;
    long long r = idx >> 6;
    float alpha = alphaP[0];
    short8v z = *(short8v*)(Z + r * 768 + c0);
    float4 w0 = *(const float4*)(w + c0);
    float4 w1 = *(const float4*)(w + c0 + 4);
    float4 b0 = *(const float4*)(b + c0);
    float4 b1 = *(const float4*)(b + c0 + 4);
    short8v o;
    o[0] = (short)f2bf(tanhfast(alpha * bf2f((u16)z[0])) * w0.x + b0.x);
    o[1] = (short)f2bf(tanhfast(alpha * bf2f((u16)z[1])) * w0.y + b0.y);
    o[2] = (short)f2bf(tanhfast(alpha * bf2f((u16)z[2])) * w0.z + b0.z);
    o[3] = (short)f2bf(tanhfast(alpha * bf2f((u16)z[3])) * w0.w + b0.w);
    o[4] = (short)f2bf(tanhfast(alpha * bf2f((u16)z[4])) * w1.x + b1.x);
    o[5] = (short)f2bf(tanhfast(alpha * bf2f((u16)z[5])) * w1.y + b1.y);
    o[6] = (short)f2bf(tanhfast(alpha * bf2f((u16)z[6])) * w1.z + b1.z);
    o[7] = (short)f2bf(tanhfast(alpha * bf2f((u16)z[7])) * w1.w + b1.w);
    *(short8v*)(Z + r * 768 + c0) = o;
}

extern "C" void kernel_launch(void* const* d_in, const int* in_sizes, int n_in,
                              void* d_out, int out_size, void* d_ws, size_t ws_size,
                              hipStream_t stream) {
    const float* x_res = (const float*)d_in[0];
    const int* eidx = (const int*)d_in[1];
    const int* cidx = (const int*)d_in[2];
    const int N = in_sizes[0] / 128;
    const int E = in_sizes[1] / 2;
    const int P = in_sizes[2] / 2;
    const int* src = eidx;
    const int* dst = eidx + E;
    const int* g1 = cidx;
    const int* g2 = cidx + P;
    const float* Wl[3] = {(const float*)d_in[3], (const float*)d_in[9],  (const float*)d_in[15]};
    const float* Wr[3] = {(const float*)d_in[4], (const float*)d_in[10], (const float*)d_in[16]};
    const float* bc[3] = {(const float*)d_in[5], (const float*)d_in[11], (const float*)d_in[17]};
    const float* gnw[3] = {(const float*)d_in[6], (const float*)d_in[12], (const float*)d_in[18]};
    const float* gnb[3] = {(const float*)d_in[7], (const float*)d_in[13], (const float*)d_in[19]};
    const float* gns[3] = {(const float*)d_in[8], (const float*)d_in[14], (const float*)d_in[20]};
    const float* alphaP = (const float*)d_in[21];
    const float* dytw = (const float*)d_in[22];
    const float* dytb = (const float*)d_in[23];
    const float* W1 = (const float*)d_in[24]; const float* b1 = (const float*)d_in[25];
    const float* W2 = (const float*)d_in[26]; const float* b2 = (const float*)d_in[27];
    const float* W3 = (const float*)d_in[28]; const float* b3 = (const float*)d_in[29];
    const float* C1 = (const float*)d_in[30]; const float* c1 = (const float*)d_in[31];
    const float* C2 = (const float*)d_in[32]; const float* c2 = (const float*)d_in[33];
    const float* C3 = (const float*)d_in[34]; const float* c3 = (const float*)d_in[35];
    float* out = (float*)d_out;

    // ---- workspace layout ----
    char* ws = (char*)d_ws;
    size_t off = 0;
    size_t zOff  = off; off += (size_t)N * 768 * 2;     off = (off + 255) & ~(size_t)255;
    size_t stOff = off; off += 4096;                    off = (off + 255) & ~(size_t)255;
    size_t zfOff = off; off += (size_t)N * 128 * 2;     off = (off + 255) & ~(size_t)255;
    size_t rpOff = off; off += (size_t)(N + 1) * 4;     off = (off + 255) & ~(size_t)255;
    size_t curOff = off; off += (size_t)N * 4;          off = (off + 255) & ~(size_t)255;
    size_t srcsOff = off; off += (size_t)E * 4;         off = (off + 255) & ~(size_t)255;
    size_t bsOff = off; off += 4096;                    off = (off + 255) & ~(size_t)255;
    static const size_t se[8] = {65536, 131072, 131072, 393216, 262144, 65536, 65536, 32768};
    short* wt[8];
    for (int i = 0; i < 8; ++i) {
        wt[i] = (short*)(ws + off);
        off += 2 * se[i];
        off = (off + 255) & ~(size_t)255;
    }
    size_t pOff = off;
    size_t avail = ws_size > pOff ? ws_size - pOff : 0;

    u16*   Z    = (u16*)(ws + zOff);
    float* st   = (float*)(ws + stOff);
    u16*   zf   = (u16*)(ws + zfOff);
    int*   rp   = (int*)(ws + rpOff);
    int*   cur  = (int*)(ws + curOff);
    int*   srcs = (int*)(ws + srcsOff);
    int*   bs   = (int*)(ws + bsOff);
    u16*   pbuf = (u16*)(ws + pOff);

    int NC = (int)((avail /  512) & ~(size_t)127); if (NC < 128) NC = 128; if (NC > N) NC = N; // m: 256 bf16/row
    int S  = (int)((avail / 2048) & ~(size_t)127); if (S  < 128) S  = 128; if (S  > N) S  = N; // t1+t2 bf16

    dim3 blk(256);

    // ---- merged weight prep ----
    {
        PrepArgs a;
        const float* Ws[11] = {Wl[0], Wr[0], Wl[1], Wr[1], Wl[2], Wr[2], W1, W2, W3, C1, C2};
        short* Os[11] = {wt[0], wt[0], wt[1], wt[1], wt[2], wt[2], wt[3], wt[4], wt[5], wt[6], wt[7]};
        int Ks[11]    = {128, 128, 256, 256, 256, 256, 768, 512, 512, 256, 256};
        int Ncs[11]   = {256, 256, 256, 256, 256, 256, 512, 512, 128, 256, 128};
        int kOffs[11] = {0, 128, 0, 256, 0, 256, 0, 0, 0, 0, 0};
        int Ktots[11] = {256, 256, 512, 512, 512, 512, 768, 512, 512, 256, 256};
        int s = 0;
        for (int i = 0; i < 11; ++i) {
            a.W[i] = Ws[i]; a.outp[i] = Os[i];
            a.K[i] = Ks[i]; a.Nc[i] = Ncs[i]; a.kOff[i] = kOffs[i]; a.Ktot[i] = Ktots[i];
            a.start[i] = s;
            s += Ks[i] * Ncs[i];
        }
        a.start[11] = s;
        prep_all_kernel<<<(s + 255) / 256, 256, 0, stream>>>(a);
    }

    // ---- CSR build ----
    int nb = (N + 255) / 256;
    hipMemsetAsync(cur, 0, (size_t)N * 4, stream);
    cnt_kernel<<<(E + 255) / 256, 256, 0, stream>>>(dst, cur, E, N);
    scan1_kernel<<<nb, 256, 0, stream>>>(cur, rp, bs, N);
    scan2_kernel<<<1, 1024, 0, stream>>>(bs, nb);
    scan3_kernel<<<nb, 256, 0, stream>>>(rp, cur, bs, N, E);
    fill_kernel<<<(E + 255) / 256, 256, 0, stream>>>(src, dst, cur, srcs, E, N);

    // ---- 3 SAGE + GELU(+stats) + GraphNorm (+res, l2:+DyT) layers ----
    u16* m = pbuf;
    for (int l = 0; l < 3; ++l) {
        u16* Zl = Z + l * 256;
        hipMemsetAsync(st, 0, 512 * 4, stream);
        for (int c0 = 0; c0 < N; c0 += NC) {
            int rows = (N - c0 < NC) ? (N - c0) : NC;
            int aggblocks = (rows + 3) / 4;
            dim3 grid(2, (rows + 127) / 128);
            if (l == 0) {
                agg_csr_kernel<true><<<aggblocks, 256, 0, stream>>>(x_res, 128, rp, srcs, m, c0, rows);
                mm_kernel<1, true, false, true, true, false><<<grid, blk, 0, stream>>>(
                    m, 128, x_res + (size_t)c0 * 128, 128, 128, 128,
                    wt[0], 256, bc[0], nullptr, 0, st, st + 256,
                    Zl + (size_t)c0 * 768, 768, rows);
            } else {
                const u16* h = Z + (l - 1) * 256;
                agg_csr_kernel<false><<<aggblocks, 256, 0, stream>>>(h, 768, rp, srcs, m, c0, rows);
                mm_kernel<1, true, true, true, true, false><<<grid, blk, 0, stream>>>(
                    m, 256, h + (size_t)c0 * 768, 768, 256, 256,
                    wt[l], 512, bc[l], nullptr, 0, st, st + 256,
                    Zl + (size_t)c0 * 768, 768, rows);
            }
        }
        const u16* prev = (l == 0) ? nullptr : (Z + (l - 1) * 256);
        int gnblocks = (int)(((long long)N * 64 + 255) / 256);
        if (l == 2)
            gn_apply_kernel<true><<<gnblocks, 256, 0, stream>>>(
                Zl, 768, prev, 768, N, st, st + 256, gnw[l], gnb[l], gns[l], 1.0f / (float)N,
                alphaP, dytw + 512, dytb + 512);
        else
            gn_apply_kernel<false><<<gnblocks, 256, 0, stream>>>(
                Zl, 768, prev, 768, N, st, st + 256, gnw[l], gnb[l], gns[l], 1.0f / (float)N,
                nullptr, nullptr, nullptr);
    }

    // ---- DynamicTanh on cols 0..511 (layer-2 slice fused into gn_apply) ----
    dyt512_kernel<<<(int)(((long long)N * 64 + 255) / 256), 256, 0, stream>>>(
        Z, alphaP, dytw, dytb, (long long)N * 64);

    // ---- node MLP, chunked (t1/t2 bf16 in scratch); W3 fuses residual + row-L2-norm ----
    {
        short* t1c = (short*)pbuf;
        short* t2c = t1c + (size_t)S * 512;
        for (int r0 = 0; r0 < N; r0 += S) {
            int rows = (N - r0 < S) ? (N - r0) : S;
            mm_kernel<1, true, true, true, false, false><<<dim3(4, (rows + 127) / 128), blk, 0, stream>>>(
                Z + (size_t)r0 * 768, 768, nullptr, 0, 768, 0,
                wt[3], 768, b1, nullptr, 0, nullptr, nullptr, t1c, 512, rows);
            mm_kernel<1, true, true, true, false, false><<<dim3(4, (rows + 127) / 128), blk, 0, stream>>>(
                t1c, 512, nullptr, 0, 512, 0,
                wt[4], 512, b2, nullptr, 0, nullptr, nullptr, t2c, 512, rows);
            mm_kernel<3, true, true, true, false, true><<<dim3(1, (rows + 127) / 128), blk, 0, stream>>>(
                t2c, 512, nullptr, 0, 512, 0,
                wt[5], 512, b3, x_res + (size_t)r0 * 128, 128, nullptr, nullptr,
                zf + (size_t)r0 * 128, 128, rows);
        }
    }

    // ---- fused pair scoring: 128 pairs/block, 8 waves ----
    pair_kernel<<<(P + 127) / 128, dim3(512), 0, stream>>>(
        zf, g1, g2, N, P, wt[6], c1, wt[7], c2, C3, c3, out);
}

// Round 17
// 3061.201 us; speedup vs baseline: 1.0529x; 1.0529x over previous
//
#include <hip/hip_runtime.h>
#include <math.h>

typedef unsigned short u16;
typedef __attribute__((ext_vector_type(8))) short short8v;   // 8 x bf16
typedef __attribute__((ext_vector_type(4))) float f32x4;

__device__ __forceinline__ float bf2f(u16 u) { return __uint_as_float((unsigned)u << 16); }
__device__ __forceinline__ u16 f2bf(float f) {
    unsigned x = __float_as_uint(f);
    unsigned r = x + 0x7FFFu + ((x >> 16) & 1u);
    return (u16)(r >> 16);
}
// fast tanh: (e^2x - 1)/(e^2x + 1); err ~1e-6
__device__ __forceinline__ float tanhfast(float x) {
    float cx = fminf(fmaxf(x, -15.f), 15.f);
    float t = __expf(2.f * cx);
    return (t - 1.f) / (t + 1.f);
}
// fast GELU (tanh form): max abs err ~3e-4 << bf16 activation rounding (~4e-3)
__device__ __forceinline__ float geluf(float x) {
    float x3 = x * x * x;
    return 0.5f * x * (1.0f + tanhfast(0.7978845608f * (x + 0.044715f * x3)));
}
// async 16B global->LDS (direct, no VGPR round-trip). lds base wave-uniform; HW adds lane*16.
__device__ __forceinline__ void gll16(const short* g, short* l) {
    __builtin_amdgcn_global_load_lds(
        (const __attribute__((address_space(1))) void*)g,
        (__attribute__((address_space(3))) void*)l, 16, 0, 0);
}

template<bool BF>
__device__ __forceinline__ float4 ld4(const void* base, long long elemOff) {
    if (BF) {
        ushort4 u = *(const ushort4*)((const u16*)base + elemOff);
        return make_float4(bf2f(u.x), bf2f(u.y), bf2f(u.z), bf2f(u.w));
    } else {
        return *(const float4*)((const float*)base + elemOff);
    }
}

// ================= CSR build =================
__global__ __launch_bounds__(256) void cnt_kernel(const int* __restrict__ dst, int* __restrict__ cnt, int E, int Nn) {
    int e = blockIdx.x * 256 + threadIdx.x;
    if (e < E) {
        int d = dst[e];
        if ((unsigned)d < (unsigned)Nn) atomicAdd(&cnt[d], 1);
    }
}
__global__ __launch_bounds__(256) void scan1_kernel(const int* __restrict__ cnt, int* __restrict__ rp,
                                                    int* __restrict__ bs, int n) {
    __shared__ int sh[256];
    int i = blockIdx.x * 256 + threadIdx.x;
    int v = (i < n) ? cnt[i] : 0;
    sh[threadIdx.x] = v; __syncthreads();
    for (int o = 1; o < 256; o <<= 1) {
        int t = (threadIdx.x >= o) ? sh[threadIdx.x - o] : 0;
        __syncthreads();
        sh[threadIdx.x] += t;
        __syncthreads();
    }
    if (i < n) rp[i] = sh[threadIdx.x] - v;
    if (threadIdx.x == 255) bs[blockIdx.x] = sh[255];
}
__global__ __launch_bounds__(1024) void scan2_kernel(int* __restrict__ bs, int nb) {
    __shared__ int sh[1024];
    int v = (threadIdx.x < nb) ? bs[threadIdx.x] : 0;
    sh[threadIdx.x] = v; __syncthreads();
    for (int o = 1; o < 1024; o <<= 1) {
        int t = (threadIdx.x >= o) ? sh[threadIdx.x - o] : 0;
        __syncthreads();
        sh[threadIdx.x] += t;
        __syncthreads();
    }
    if (threadIdx.x < nb) bs[threadIdx.x] = sh[threadIdx.x] - v;
}
__global__ __launch_bounds__(256) void scan3_kernel(int* __restrict__ rp, int* __restrict__ cur,
                                                    const int* __restrict__ bs, int n, int E) {
    int i = blockIdx.x * 256 + threadIdx.x;
    if (i < n) {
        int v = rp[i] + bs[blockIdx.x];
        rp[i] = v;
        cur[i] = v;
    }
    if (i == 0) rp[n] = E;
}
__global__ __launch_bounds__(256) void fill_kernel(const int* __restrict__ src, const int* __restrict__ dst,
                                                   int* __restrict__ cur, int* __restrict__ srcs, int E, int Nn) {
    int e = blockIdx.x * 256 + threadIdx.x;
    if (e >= E) return;
    int d = dst[e];
    if ((unsigned)d >= (unsigned)Nn) return;
    int s = src[e];
    if ((unsigned)s >= (unsigned)Nn) s = 0;
    int p = atomicAdd(&cur[d], 1);
    srcs[p] = s;
}

// ================= CSR mean-aggregation -> bf16 m (4-way ILP) =================
template<bool L0>
__global__ __launch_bounds__(256) void agg_csr_kernel(const void* __restrict__ X, int ldx,
    const int* __restrict__ rp, const int* __restrict__ srcs,
    u16* __restrict__ m, int c0, int rows)
{
    int lrow = blockIdx.x * 4 + (threadIdx.x >> 6);
    if (lrow >= rows) return;
    int lane = threadIdx.x & 63;
    int r = c0 + lrow;
    int b = rp[r], e = rp[r + 1];
    float inv = 1.0f / fmaxf((float)(e - b), 1.0f);
    if (L0) {
        float a0 = 0.f, a1 = 0.f, b0 = 0.f, b1 = 0.f;
        float c0a = 0.f, c1a = 0.f, d0 = 0.f, d1 = 0.f;
        int i = b;
        for (; i + 4 <= e; i += 4) {
            int s0 = srcs[i], s1 = srcs[i + 1], s2 = srcs[i + 2], s3 = srcs[i + 3];
            float2 v0 = *(const float2*)((const float*)X + (long long)s0 * ldx + lane * 2);
            float2 v1 = *(const float2*)((const float*)X + (long long)s1 * ldx + lane * 2);
            float2 v2 = *(const float2*)((const float*)X + (long long)s2 * ldx + lane * 2);
            float2 v3 = *(const float2*)((const float*)X + (long long)s3 * ldx + lane * 2);
            a0 += v0.x; a1 += v0.y;
            b0 += v1.x; b1 += v1.y;
            c0a += v2.x; c1a += v2.y;
            d0 += v3.x; d1 += v3.y;
        }
        for (; i < e; ++i) {
            int s0 = srcs[i];
            float2 v0 = *(const float2*)((const float*)X + (long long)s0 * ldx + lane * 2);
            a0 += v0.x; a1 += v0.y;
        }
        a0 += b0 + c0a + d0; a1 += b1 + c1a + d1;
        ushort2 o; o.x = f2bf(a0 * inv); o.y = f2bf(a1 * inv);
        *(ushort2*)(m + (long long)lrow * 128 + lane * 2) = o;
    } else {
        float a0 = 0.f, a1 = 0.f, a2 = 0.f, a3 = 0.f;
        float b0 = 0.f, b1 = 0.f, b2 = 0.f, b3 = 0.f;
        float c0_ = 0.f, c1_ = 0.f, c2_ = 0.f, c3_ = 0.f;
        float d0 = 0.f, d1 = 0.f, d2 = 0.f, d3 = 0.f;
        int i = b;
        for (; i + 4 <= e; i += 4) {
            int s0 = srcs[i], s1 = srcs[i + 1], s2 = srcs[i + 2], s3 = srcs[i + 3];
            ushort4 u0 = *(const ushort4*)((const u16*)X + (long long)s0 * ldx + lane * 4);
            ushort4 u1 = *(const ushort4*)((const u16*)X + (long long)s1 * ldx + lane * 4);
            ushort4 u2 = *(const ushort4*)((const u16*)X + (long long)s2 * ldx + lane * 4);
            ushort4 u3 = *(const ushort4*)((const u16*)X + (long long)s3 * ldx + lane * 4);
            a0 += bf2f(u0.x); a1 += bf2f(u0.y); a2 += bf2f(u0.z); a3 += bf2f(u0.w);
            b0 += bf2f(u1.x); b1 += bf2f(u1.y); b2 += bf2f(u1.z); b3 += bf2f(u1.w);
            c0_ += bf2f(u2.x); c1_ += bf2f(u2.y); c2_ += bf2f(u2.z); c3_ += bf2f(u2.w);
            d0 += bf2f(u3.x); d1 += bf2f(u3.y); d2 += bf2f(u3.z); d3 += bf2f(u3.w);
        }
        for (; i < e; ++i) {
            int s0 = srcs[i];
            ushort4 u0 = *(const ushort4*)((const u16*)X + (long long)s0 * ldx + lane * 4);
            a0 += bf2f(u0.x); a1 += bf2f(u0.y); a2 += bf2f(u0.z); a3 += bf2f(u0.w);
        }
        a0 += b0 + c0_ + d0; a1 += b1 + c1_ + d1;
        a2 += b2 + c2_ + d2; a3 += b3 + c3_ + d3;
        ushort4 o;
        o.x = f2bf(a0 * inv); o.y = f2bf(a1 * inv); o.z = f2bf(a2 * inv); o.w = f2bf(a3 * inv);
        *(ushort4*)(m + (long long)lrow * 256 + lane * 4) = o;
    }
}

// ================= merged weight prep =================
struct PrepArgs {
    const float* W[11];
    short* outp[11];
    int K[11], Nc[11], kOff[11], Ktot[11];
    int start[12];
};
__global__ __launch_bounds__(256) void prep_all_kernel(PrepArgs a) {
    int idx = blockIdx.x * 256 + threadIdx.x;
    if (idx >= a.start[11]) return;
    int si = 0;
    #pragma unroll
    for (int j = 1; j < 11; ++j) si += (idx >= a.start[j]);
    int local = idx - a.start[si];
    int Nc = a.Nc[si];
    int k = local / Nc, n = local % Nc;
    a.outp[si][(long long)n * a.Ktot[si] + a.kOff[si] + k] = (short)f2bf(a.W[si][local]);
}

// ---------------- fp32 staging helper (reg path) ----------------
__device__ __forceinline__ void loadrow32(const float* p, short8v& o0, short8v& o1) {
    float4 a = *(const float4*)p;
    float4 b = *(const float4*)(p + 4);
    float4 c = *(const float4*)(p + 8);
    float4 d = *(const float4*)(p + 12);
    short8v r0, r1;
    r0[0] = (short)f2bf(a.x); r0[1] = (short)f2bf(a.y); r0[2] = (short)f2bf(a.z); r0[3] = (short)f2bf(a.w);
    r0[4] = (short)f2bf(b.x); r0[5] = (short)f2bf(b.y); r0[6] = (short)f2bf(b.z); r0[7] = (short)f2bf(b.w);
    r1[0] = (short)f2bf(c.x); r1[1] = (short)f2bf(c.y); r1[2] = (short)f2bf(c.z); r1[3] = (short)f2bf(c.w);
    r1[4] = (short)f2bf(d.x); r1[5] = (short)f2bf(d.y); r1[6] = (short)f2bf(d.z); r1[7] = (short)f2bf(d.w);
    o0 = r0; o1 = r1;
}

// ================= MFMA GEMM v3: async staging + chunk-XOR bank swizzle =================
template<int EPI, bool A1BF, bool A2BF, bool CBF, bool STAT, bool NORM>
__global__ __launch_bounds__(256) void mm_kernel(
    const void* __restrict__ A1, int lda1,
    const void* __restrict__ A2, int lda2,
    int K1, int K2,
    const short* __restrict__ Bhi, int ldb,
    const float* __restrict__ bias,
    const float* __restrict__ resid, int ldres,
    float* __restrict__ s1, float* __restrict__ s2,
    void* __restrict__ C, int ldc, int M)
{
    __shared__ short AsL[4096];      // [128][32] linear, chunk-swizzled content
    __shared__ short BhL[4096];
    __shared__ float cst[256];       // STAT: colsum[128] | colsq[128]
    __shared__ float rsq[128][2];    // NORM
    const int t = threadIdx.x;
    const int rowbase = blockIdx.y * 128;
    const int colbase = blockIdx.x * 128;
    const int lane = t & 63;
    const int wv = t >> 6;
    const int wr = (wv >> 1) << 6;
    const int wc = (wv & 1) << 6;
    const int l15 = lane & 15;
    const int rgrp = (lane >> 4) << 2;
    const int lr16 = lane >> 2;            // 0..15
    const int swz = (((lane & 3) ^ (lr16 & 3)) << 3);   // swizzled global elem offset
    const int ldsW = wv * 512;             // wave-uniform LDS elem base
    const int rdk = (((lane >> 4) ^ (l15 & 3)) << 3);   // read-side swizzled k offset
    if (STAT && t < 256) cst[t] = 0.f;
    f32x4 acc[4][4] = {};
    const int k1t = K1 >> 5;
    const int KT = (K1 + K2) >> 5;

    for (int kt = 0; kt < KT; ++kt) {
        const bool p1 = kt < k1t;
        const int kbl = (p1 ? kt : kt - k1t) << 5;
        {
            long long kb = (long long)(kt << 5) + swz;
            int r0 = colbase + wv * 16 + lr16;
            gll16(Bhi + (long long)r0 * ldb + kb, BhL + ldsW);
            gll16(Bhi + (long long)(r0 + 64) * ldb + kb, BhL + 2048 + ldsW);
        }
        if (p1 ? A1BF : A2BF) {
            const short* Ab = (const short*)(p1 ? A1 : A2);
            const int lda = p1 ? lda1 : lda2;
            int r0 = rowbase + wv * 16 + lr16;      if (r0 >= M) r0 = M - 1;
            int r1 = rowbase + 64 + wv * 16 + lr16; if (r1 >= M) r1 = M - 1;
            gll16(Ab + (long long)r0 * lda + kbl + swz, AsL + ldsW);
            gll16(Ab + (long long)r1 * lda + kbl + swz, AsL + 2048 + ldsW);
        } else {
            const float* Ab = (const float*)(p1 ? A1 : A2);
            const int lda = p1 ? lda1 : lda2;
            int row = t >> 1, h = (t & 1) << 1;
            int r = rowbase + row;
            short8v o0 = {0,0,0,0,0,0,0,0}, o1 = {0,0,0,0,0,0,0,0};
            if (r < M) loadrow32(Ab + (long long)r * lda + kbl + (h << 3), o0, o1);
            *(short8v*)&AsL[row * 32 + ((h ^ (row & 3)) << 3)]       = o0;
            *(short8v*)&AsL[row * 32 + (((h + 1) ^ (row & 3)) << 3)] = o1;
        }
        __syncthreads();
        short8v a4[4], b4[4];
        #pragma unroll
        for (int mr = 0; mr < 4; ++mr)
            a4[mr] = *(short8v*)&AsL[(wr + mr * 16 + l15) * 32 + rdk];
        #pragma unroll
        for (int nr = 0; nr < 4; ++nr)
            b4[nr] = *(short8v*)&BhL[(wc + nr * 16 + l15) * 32 + rdk];
        #pragma unroll
        for (int mr = 0; mr < 4; ++mr)
            #pragma unroll
            for (int nr = 0; nr < 4; ++nr)
                acc[mr][nr] = __builtin_amdgcn_mfma_f32_16x16x32_bf16(a4[mr], b4[nr], acc[mr][nr], 0, 0, 0);
        __syncthreads();
    }

    if (NORM) {
        float rs[4][4] = {};
        #pragma unroll
        for (int nr = 0; nr < 4; ++nr) {
            int c = colbase + wc + nr * 16 + l15;
            float bi = bias[c];
            #pragma unroll
            for (int mr = 0; mr < 4; ++mr)
                #pragma unroll
                for (int i = 0; i < 4; ++i) {
                    int r = rowbase + wr + mr * 16 + rgrp + i;
                    float v = 0.f;
                    if (r < M) {
                        v = acc[mr][nr][i] + bi;
                        if (EPI == 3) v += resid[(long long)r * ldres + c];
                        if (EPI == 1) v = geluf(v);
                    }
                    acc[mr][nr][i] = v;
                    rs[mr][i] += v * v;
                }
        }
        #pragma unroll
        for (int mr = 0; mr < 4; ++mr)
            #pragma unroll
            for (int i = 0; i < 4; ++i) {
                float s = rs[mr][i];
                s += __shfl_xor(s, 1); s += __shfl_xor(s, 2);
                s += __shfl_xor(s, 4); s += __shfl_xor(s, 8);
                rs[mr][i] = s;
            }
        if (l15 == 0) {
            #pragma unroll
            for (int mr = 0; mr < 4; ++mr)
                #pragma unroll
                for (int i = 0; i < 4; ++i)
                    rsq[wr + mr * 16 + rgrp + i][wv & 1] = rs[mr][i];
        }
        __syncthreads();
        #pragma unroll
        for (int mr = 0; mr < 4; ++mr)
            #pragma unroll
            for (int i = 0; i < 4; ++i) {
                int rl = wr + mr * 16 + rgrp + i;
                int r = rowbase + rl;
                if (r >= M) continue;
                float inv = 1.0f / (sqrtf(rsq[rl][0] + rsq[rl][1]) + 1e-10f);
                #pragma unroll
                for (int nr = 0; nr < 4; ++nr) {
                    int c = colbase + wc + nr * 16 + l15;
                    float v = acc[mr][nr][i] * inv;
                    if (CBF) ((u16*)C)[(long long)r * ldc + c] = f2bf(v);
                    else     ((float*)C)[(long long)r * ldc + c] = v;
                }
            }
    } else {
        #pragma unroll
        for (int nr = 0; nr < 4; ++nr) {
            int c = colbase + wc + nr * 16 + l15;
            float bi = bias[c];
            float cp = 0.f, cq = 0.f;
            #pragma unroll
            for (int mr = 0; mr < 4; ++mr)
                #pragma unroll
                for (int i = 0; i < 4; ++i) {
                    int r = rowbase + wr + mr * 16 + rgrp + i;
                    if (r >= M) continue;
                    float v = acc[mr][nr][i] + bi;
                    if (EPI == 1) v = geluf(v);
                    if (EPI == 3) v += resid[(long long)r * ldres + c];
                    if (CBF) ((u16*)C)[(long long)r * ldc + c] = f2bf(v);
                    else     ((float*)C)[(long long)r * ldc + c] = v;
                    if (STAT) { cp += v; cq += v * v; }
                }
            if (STAT) {
                cp += __shfl_xor(cp, 16); cp += __shfl_xor(cp, 32);
                cq += __shfl_xor(cq, 16); cq += __shfl_xor(cq, 32);
                if (lane < 16) {
                    int cl = wc + nr * 16 + l15;
                    atomicAdd(&cst[cl], cp);
                    atomicAdd(&cst[128 + cl], cq);
                }
            }
        }
        if (STAT) {
            __syncthreads();
            if (t < 128) {
                atomicAdd(s1 + colbase + t, cst[t]);
                atomicAdd(s2 + colbase + t, cst[128 + t]);
            }
        }
    }
}

// ================= pair kernel (r15 best config: 64 pairs/block, 4 waves, hoisted A) =================
__global__ __launch_bounds__(256) void pair_kernel(
    const u16* __restrict__ zf,
    const int* __restrict__ g1, const int* __restrict__ g2,
    int Nn, int P,
    const short* __restrict__ C1t, const float* __restrict__ c1,
    const short* __restrict__ C2t, const float* __restrict__ c2,
    const float* __restrict__ C3, const float* __restrict__ c3,
    float* __restrict__ out)
{
    __shared__ short E1s[64 * 264];
    __shared__ float sc[64][2];
    const int t = threadIdx.x;
    const int lane = t & 63;
    const int wv = t >> 6;
    const int wr = (wv >> 1) << 5;   // 0 / 32
    const int wc = (wv & 1) << 6;    // 0 / 64
    const int l15 = lane & 15;
    const int kreg = (lane >> 4) << 3;
    const int rgrp = (lane >> 4) << 2;
    const int p0 = blockIdx.x * 64;

    int gidx[2][2];
    #pragma unroll
    for (int mr = 0; mr < 2; ++mr) {
        int pr = p0 + wr + mr * 16 + l15;
        int a = (pr < P) ? g1[pr] : 0;  if ((unsigned)a >= (unsigned)Nn) a = 0;
        gidx[0][mr] = a;
        int b = (pr < P) ? g2[pr] : 0;  if ((unsigned)b >= (unsigned)Nn) b = 0;
        gidx[1][mr] = b;
    }

    short8v az[2][2][4];   // [half][mr][ktl]
    #pragma unroll
    for (int half = 0; half < 2; ++half)
        #pragma unroll
        for (int mr = 0; mr < 2; ++mr)
            #pragma unroll
            for (int ktl = 0; ktl < 4; ++ktl)
                az[half][mr][ktl] = *(const short8v*)((const short*)zf
                    + (long long)gidx[half][mr] * 128 + (ktl << 5) + kreg);

    #pragma unroll
    for (int ch = 0; ch < 2; ++ch) {
        f32x4 acc1[2][4] = {};
        #pragma unroll
        for (int kt = 0; kt < 8; ++kt) {
            const int half = kt >> 2;
            const int ktl = kt & 3;
            short8v b4[4];
            #pragma unroll
            for (int nr = 0; nr < 4; ++nr)
                b4[nr] = *(const short8v*)(C1t + (long long)(ch * 128 + wc + nr * 16 + l15) * 256 + (kt << 5) + kreg);
            #pragma unroll
            for (int mr = 0; mr < 2; ++mr)
                #pragma unroll
                for (int nr = 0; nr < 4; ++nr)
                    acc1[mr][nr] = __builtin_amdgcn_mfma_f32_16x16x32_bf16(az[half][mr][ktl], b4[nr], acc1[mr][nr], 0, 0, 0);
        }
        #pragma unroll
        for (int nr = 0; nr < 4; ++nr) {
            int cc = wc + nr * 16 + l15;
            float bi = c1[ch * 128 + cc];
            #pragma unroll
            for (int mr = 0; mr < 2; ++mr)
                #pragma unroll
                for (int i = 0; i < 4; ++i) {
                    float v = geluf(acc1[mr][nr][i] + bi);
                    E1s[(wr + mr * 16 + rgrp + i) * 264 + ch * 128 + cc] = (short)f2bf(v);
                }
        }
    }
    __syncthreads();

    f32x4 acc[2][4] = {};
    #pragma unroll
    for (int kt = 0; kt < 8; ++kt) {
        short8v a4[2], b4[4];
        #pragma unroll
        for (int mr = 0; mr < 2; ++mr)
            a4[mr] = *(short8v*)&E1s[(wr + mr * 16 + l15) * 264 + (kt << 5) + kreg];
        #pragma unroll
        for (int nr = 0; nr < 4; ++nr)
            b4[nr] = *(const short8v*)(C2t + (long long)(wc + nr * 16 + l15) * 256 + (kt << 5) + kreg);
        #pragma unroll
        for (int mr = 0; mr < 2; ++mr)
            #pragma unroll
            for (int nr = 0; nr < 4; ++nr)
                acc[mr][nr] = __builtin_amdgcn_mfma_f32_16x16x32_bf16(a4[mr], b4[nr], acc[mr][nr], 0, 0, 0);
    }

    float pr_[2][4] = {};
    #pragma unroll
    for (int nr = 0; nr < 4; ++nr) {
        int cc = wc + nr * 16 + l15;
        float bi = c2[cc];
        float w3 = C3[cc];
        #pragma unroll
        for (int mr = 0; mr < 2; ++mr)
            #pragma unroll
            for (int i = 0; i < 4; ++i)
                pr_[mr][i] += geluf(acc[mr][nr][i] + bi) * w3;
    }
    #pragma unroll
    for (int mr = 0; mr < 2; ++mr)
        #pragma unroll
        for (int i = 0; i < 4; ++i) {
            float s = pr_[mr][i];
            s += __shfl_xor(s, 1); s += __shfl_xor(s, 2);
            s += __shfl_xor(s, 4); s += __shfl_xor(s, 8);
            pr_[mr][i] = s;
        }
    if (l15 == 0) {
        #pragma unroll
        for (int mr = 0; mr < 2; ++mr)
            #pragma unroll
            for (int i = 0; i < 4; ++i)
                sc[wr + mr * 16 + rgrp + i][wv & 1] = pr_[mr][i];
    }
    __syncthreads();
    if (t < 64) {
        int p = p0 + t;
        if (p < P) {
            float x = sc[t][0] + sc[t][1] + c3[0];
            out[p] = 1.0f / (1.0f + expf(-x));
        }
    }
}

// ---------------- GraphNorm apply (+res, + optional fused DyT), bf16 in place ----------------
template<bool DYT>
__global__ __launch_bounds__(256) void gn_apply_kernel(u16* __restrict__ G, int ldg,
    const u16* __restrict__ prev, int ldp, int M,
    const float* __restrict__ s1, const float* __restrict__ s2,
    const float* __restrict__ gw, const float* __restrict__ gb, const float* __restrict__ gs,
    float invN,
    const float* __restrict__ dA, const float* __restrict__ dW, const float* __restrict__ dB)
{
    long long idx = (long long)blockIdx.x * blockDim.x + threadIdx.x;
    if (idx >= (long long)M * 64) return;
    int c0 = (int)(idx & 63) << 2;
    long long r = idx >> 6;
    float4 g = ld4<true>(G, r * ldg + c0);
    float o[4] = {g.x, g.y, g.z, g.w};
    float alpha = DYT ? dA[0] : 0.f;
    #pragma unroll
    for (int j = 0; j < 4; ++j) {
        int c = c0 + j;
        float mu = s1[c] * invN;
        float ms = gs[c];
        float var = s2[c] * invN - mu * mu * ms * (2.0f - ms);
        float rstd = rsqrtf(var + 1e-5f);
        o[j] = (o[j] - ms * mu) * rstd * gw[c] + gb[c];
    }
    if (prev) {
        float4 pv = ld4<true>(prev, r * ldp + c0);
        o[0] += pv.x; o[1] += pv.y; o[2] += pv.z; o[3] += pv.w;
    }
    if (DYT) {
        #pragma unroll
        for (int j = 0; j < 4; ++j)
            o[j] = tanhfast(alpha * o[j]) * dW[c0 + j] + dB[c0 + j];
    }
    ushort4 u; u.x = f2bf(o[0]); u.y = f2bf(o[1]); u.z = f2bf(o[2]); u.w = f2bf(o[3]);
    *(ushort4*)((u16*)G + r * ldg + c0) = u;
}

// ---------------- DynamicTanh on cols 0..511 of Z[N,768] ----------------
__global__ __launch_bounds__(256) void dyt512_kernel(u16* __restrict__ Z,
    const float* __restrict__ alphaP, const float* __restrict__ w, const float* __restrict__ b,
    long long total)   // rows * 64
{
    long long idx = (long long)blockIdx.x * blockDim.x + threadIdx.x;
    if (idx >= total) return;
    int c0 = (int)(idx & 63) << 3;
    long long r = idx >> 6;
    float alpha = alphaP[0];
    short8v z = *(short8v*)(Z + r * 768 + c0);
    float4 w0 = *(const float4*)(w + c0);
    float4 w1 = *(const float4*)(w + c0 + 4);
    float4 b0 = *(const float4*)(b + c0);
    float4 b1 = *(const float4*)(b + c0 + 4);
    short8v o;
    o[0] = (short)f2bf(tanhfast(alpha * bf2f((u16)z[0])) * w0.x + b0.x);
    o[1] = (short)f2bf(tanhfast(alpha * bf2f((u16)z[1])) * w0.y + b0.y);
    o[2] = (short)f2bf(tanhfast(alpha * bf2f((u16)z[2])) * w0.z + b0.z);
    o[3] = (short)f2bf(tanhfast(alpha * bf2f((u16)z[3])) * w0.w + b0.w);
    o[4] = (short)f2bf(tanhfast(alpha * bf2f((u16)z[4])) * w1.x + b1.x);
    o[5] = (short)f2bf(tanhfast(alpha * bf2f((u16)z[5])) * w1.y + b1.y);
    o[6] = (short)f2bf(tanhfast(alpha * bf2f((u16)z[6])) * w1.z + b1.z);
    o[7] = (short)f2bf(tanhfast(alpha * bf2f((u16)z[7])) * w1.w + b1.w);
    *(short8v*)(Z + r * 768 + c0) = o;
}

extern "C" void kernel_launch(void* const* d_in, const int* in_sizes, int n_in,
                              void* d_out, int out_size, void* d_ws, size_t ws_size,
                              hipStream_t stream) {
    const float* x_res = (const float*)d_in[0];
    const int* eidx = (const int*)d_in[1];
    const int* cidx = (const int*)d_in[2];
    const int N = in_sizes[0] / 128;
    const int E = in_sizes[1] / 2;
    const int P = in_sizes[2] / 2;
    const int* src = eidx;
    const int* dst = eidx + E;
    const int* g1 = cidx;
    const int* g2 = cidx + P;
    const float* Wl[3] = {(const float*)d_in[3], (const float*)d_in[9],  (const float*)d_in[15]};
    const float* Wr[3] = {(const float*)d_in[4], (const float*)d_in[10], (const float*)d_in[16]};
    const float* bc[3] = {(const float*)d_in[5], (const float*)d_in[11], (const float*)d_in[17]};
    const float* gnw[3] = {(const float*)d_in[6], (const float*)d_in[12], (const float*)d_in[18]};
    const float* gnb[3] = {(const float*)d_in[7], (const float*)d_in[13], (const float*)d_in[19]};
    const float* gns[3] = {(const float*)d_in[8], (const float*)d_in[14], (const float*)d_in[20]};
    const float* alphaP = (const float*)d_in[21];
    const float* dytw = (const float*)d_in[22];
    const float* dytb = (const float*)d_in[23];
    const float* W1 = (const float*)d_in[24]; const float* b1 = (const float*)d_in[25];
    const float* W2 = (const float*)d_in[26]; const float* b2 = (const float*)d_in[27];
    const float* W3 = (const float*)d_in[28]; const float* b3 = (const float*)d_in[29];
    const float* C1 = (const float*)d_in[30]; const float* c1 = (const float*)d_in[31];
    const float* C2 = (const float*)d_in[32]; const float* c2 = (const float*)d_in[33];
    const float* C3 = (const float*)d_in[34]; const float* c3 = (const float*)d_in[35];
    float* out = (float*)d_out;

    // ---- workspace layout ----
    char* ws = (char*)d_ws;
    size_t off = 0;
    size_t zOff  = off; off += (size_t)N * 768 * 2;     off = (off + 255) & ~(size_t)255;
    size_t stOff = off; off += 4096;                    off = (off + 255) & ~(size_t)255;
    size_t zfOff = off; off += (size_t)N * 128 * 2;     off = (off + 255) & ~(size_t)255;
    size_t rpOff = off; off += (size_t)(N + 1) * 4;     off = (off + 255) & ~(size_t)255;
    size_t curOff = off; off += (size_t)N * 4;          off = (off + 255) & ~(size_t)255;
    size_t srcsOff = off; off += (size_t)E * 4;         off = (off + 255) & ~(size_t)255;
    size_t bsOff = off; off += 4096;                    off = (off + 255) & ~(size_t)255;
    static const size_t se[8] = {65536, 131072, 131072, 393216, 262144, 65536, 65536, 32768};
    short* wt[8];
    for (int i = 0; i < 8; ++i) {
        wt[i] = (short*)(ws + off);
        off += 2 * se[i];
        off = (off + 255) & ~(size_t)255;
    }
    size_t pOff = off;
    size_t avail = ws_size > pOff ? ws_size - pOff : 0;

    u16*   Z    = (u16*)(ws + zOff);
    float* st   = (float*)(ws + stOff);
    u16*   zf   = (u16*)(ws + zfOff);
    int*   rp   = (int*)(ws + rpOff);
    int*   cur  = (int*)(ws + curOff);
    int*   srcs = (int*)(ws + srcsOff);
    int*   bs   = (int*)(ws + bsOff);
    u16*   pbuf = (u16*)(ws + pOff);

    int NC = (int)((avail /  512) & ~(size_t)127); if (NC < 128) NC = 128; if (NC > N) NC = N; // m: 256 bf16/row
    int S  = (int)((avail / 2048) & ~(size_t)127); if (S  < 128) S  = 128; if (S  > N) S  = N; // t1+t2 bf16

    dim3 blk(256);

    // ---- merged weight prep ----
    {
        PrepArgs a;
        const float* Ws[11] = {Wl[0], Wr[0], Wl[1], Wr[1], Wl[2], Wr[2], W1, W2, W3, C1, C2};
        short* Os[11] = {wt[0], wt[0], wt[1], wt[1], wt[2], wt[2], wt[3], wt[4], wt[5], wt[6], wt[7]};
        int Ks[11]    = {128, 128, 256, 256, 256, 256, 768, 512, 512, 256, 256};
        int Ncs[11]   = {256, 256, 256, 256, 256, 256, 512, 512, 128, 256, 128};
        int kOffs[11] = {0, 128, 0, 256, 0, 256, 0, 0, 0, 0, 0};
        int Ktots[11] = {256, 256, 512, 512, 512, 512, 768, 512, 512, 256, 256};
        int s = 0;
        for (int i = 0; i < 11; ++i) {
            a.W[i] = Ws[i]; a.outp[i] = Os[i];
            a.K[i] = Ks[i]; a.Nc[i] = Ncs[i]; a.kOff[i] = kOffs[i]; a.Ktot[i] = Ktots[i];
            a.start[i] = s;
            s += Ks[i] * Ncs[i];
        }
        a.start[11] = s;
        prep_all_kernel<<<(s + 255) / 256, 256, 0, stream>>>(a);
    }

    // ---- CSR build ----
    int nb = (N + 255) / 256;
    hipMemsetAsync(cur, 0, (size_t)N * 4, stream);
    cnt_kernel<<<(E + 255) / 256, 256, 0, stream>>>(dst, cur, E, N);
    scan1_kernel<<<nb, 256, 0, stream>>>(cur, rp, bs, N);
    scan2_kernel<<<1, 1024, 0, stream>>>(bs, nb);
    scan3_kernel<<<nb, 256, 0, stream>>>(rp, cur, bs, N, E);
    fill_kernel<<<(E + 255) / 256, 256, 0, stream>>>(src, dst, cur, srcs, E, N);

    // ---- 3 SAGE + GELU(+stats) + GraphNorm (+res, l2:+DyT) layers ----
    u16* m = pbuf;
    for (int l = 0; l < 3; ++l) {
        u16* Zl = Z + l * 256;
        hipMemsetAsync(st, 0, 512 * 4, stream);
        for (int c0 = 0; c0 < N; c0 += NC) {
            int rows = (N - c0 < NC) ? (N - c0) : NC;
            int aggblocks = (rows + 3) / 4;
            dim3 grid(2, (rows + 127) / 128);
            if (l == 0) {
                agg_csr_kernel<true><<<aggblocks, 256, 0, stream>>>(x_res, 128, rp, srcs, m, c0, rows);
                mm_kernel<1, true, false, true, true, false><<<grid, blk, 0, stream>>>(
                    m, 128, x_res + (size_t)c0 * 128, 128, 128, 128,
                    wt[0], 256, bc[0], nullptr, 0, st, st + 256,
                    Zl + (size_t)c0 * 768, 768, rows);
            } else {
                const u16* h = Z + (l - 1) * 256;
                agg_csr_kernel<false><<<aggblocks, 256, 0, stream>>>(h, 768, rp, srcs, m, c0, rows);
                mm_kernel<1, true, true, true, true, false><<<grid, blk, 0, stream>>>(
                    m, 256, h + (size_t)c0 * 768, 768, 256, 256,
                    wt[l], 512, bc[l], nullptr, 0, st, st + 256,
                    Zl + (size_t)c0 * 768, 768, rows);
            }
        }
        const u16* prev = (l == 0) ? nullptr : (Z + (l - 1) * 256);
        int gnblocks = (int)(((long long)N * 64 + 255) / 256);
        if (l == 2)
            gn_apply_kernel<true><<<gnblocks, 256, 0, stream>>>(
                Zl, 768, prev, 768, N, st, st + 256, gnw[l], gnb[l], gns[l], 1.0f / (float)N,
                alphaP, dytw + 512, dytb + 512);
        else
            gn_apply_kernel<false><<<gnblocks, 256, 0, stream>>>(
                Zl, 768, prev, 768, N, st, st + 256, gnw[l], gnb[l], gns[l], 1.0f / (float)N,
                nullptr, nullptr, nullptr);
    }

    // ---- DynamicTanh on cols 0..511 (layer-2 slice fused into gn_apply) ----
    dyt512_kernel<<<(int)(((long long)N * 64 + 255) / 256), 256, 0, stream>>>(
        Z, alphaP, dytw, dytb, (long long)N * 64);

    // ---- node MLP, chunked (t1/t2 bf16 in scratch); W3 fuses residual + row-L2-norm ----
    {
        short* t1c = (short*)pbuf;
        short* t2c = t1c + (size_t)S * 512;
        for (int r0 = 0; r0 < N; r0 += S) {
            int rows = (N - r0 < S) ? (N - r0) : S;
            mm_kernel<1, true, true, true, false, false><<<dim3(4, (rows + 127) / 128), blk, 0, stream>>>(
                Z + (size_t)r0 * 768, 768, nullptr, 0, 768, 0,
                wt[3], 768, b1, nullptr, 0, nullptr, nullptr, t1c, 512, rows);
            mm_kernel<1, true, true, true, false, false><<<dim3(4, (rows + 127) / 128), blk, 0, stream>>>(
                t1c, 512, nullptr, 0, 512, 0,
                wt[4], 512, b2, nullptr, 0, nullptr, nullptr, t2c, 512, rows);
            mm_kernel<3, true, true, true, false, true><<<dim3(1, (rows + 127) / 128), blk, 0, stream>>>(
                t2c, 512, nullptr, 0, 512, 0,
                wt[5], 512, b3, x_res + (size_t)r0 * 128, 128, nullptr, nullptr,
                zf + (size_t)r0 * 128, 128, rows);
        }
    }

    // ---- fused pair scoring: e1 (from L3-resident zf) + e2 + score ----
    pair_kernel<<<(P + 63) / 64, blk, 0, stream>>>(
        zf, g1, g2, N, P, wt[6], c1, wt[7], c2, C3, c3, out);
}

// Round 18
// 3060.616 us; speedup vs baseline: 1.0531x; 1.0002x over previous
//
#include <hip/hip_runtime.h>
#include <math.h>

typedef unsigned short u16;
typedef __attribute__((ext_vector_type(8))) short short8v;   // 8 x bf16
typedef __attribute__((ext_vector_type(4))) float f32x4;

__device__ __forceinline__ float bf2f(u16 u) { return __uint_as_float((unsigned)u << 16); }
__device__ __forceinline__ u16 f2bf(float f) {
    unsigned x = __float_as_uint(f);
    unsigned r = x + 0x7FFFu + ((x >> 16) & 1u);
    return (u16)(r >> 16);
}
// fast tanh: (e^2x - 1)/(e^2x + 1); err ~1e-6
__device__ __forceinline__ float tanhfast(float x) {
    float cx = fminf(fmaxf(x, -15.f), 15.f);
    float t = __expf(2.f * cx);
    return (t - 1.f) / (t + 1.f);
}
// fast GELU (tanh form): max abs err ~3e-4 << bf16 activation rounding (~4e-3)
__device__ __forceinline__ float geluf(float x) {
    float x3 = x * x * x;
    return 0.5f * x * (1.0f + tanhfast(0.7978845608f * (x + 0.044715f * x3)));
}
// async 16B global->LDS (direct, no VGPR round-trip). lds base wave-uniform; HW adds lane*16.
__device__ __forceinline__ void gll16(const short* g, short* l) {
    __builtin_amdgcn_global_load_lds(
        (const __attribute__((address_space(1))) void*)g,
        (__attribute__((address_space(3))) void*)l, 16, 0, 0);
}

template<bool BF>
__device__ __forceinline__ float4 ld4(const void* base, long long elemOff) {
    if (BF) {
        ushort4 u = *(const ushort4*)((const u16*)base + elemOff);
        return make_float4(bf2f(u.x), bf2f(u.y), bf2f(u.z), bf2f(u.w));
    } else {
        return *(const float4*)((const float*)base + elemOff);
    }
}

// ================= CSR build =================
__global__ __launch_bounds__(256) void cnt_kernel(const int* __restrict__ dst, int* __restrict__ cnt, int E, int Nn) {
    int e = blockIdx.x * 256 + threadIdx.x;
    if (e < E) {
        int d = dst[e];
        if ((unsigned)d < (unsigned)Nn) atomicAdd(&cnt[d], 1);
    }
}
__global__ __launch_bounds__(256) void scan1_kernel(const int* __restrict__ cnt, int* __restrict__ rp,
                                                    int* __restrict__ bs, int n) {
    __shared__ int sh[256];
    int i = blockIdx.x * 256 + threadIdx.x;
    int v = (i < n) ? cnt[i] : 0;
    sh[threadIdx.x] = v; __syncthreads();
    for (int o = 1; o < 256; o <<= 1) {
        int t = (threadIdx.x >= o) ? sh[threadIdx.x - o] : 0;
        __syncthreads();
        sh[threadIdx.x] += t;
        __syncthreads();
    }
    if (i < n) rp[i] = sh[threadIdx.x] - v;
    if (threadIdx.x == 255) bs[blockIdx.x] = sh[255];
}
__global__ __launch_bounds__(1024) void scan2_kernel(int* __restrict__ bs, int nb) {
    __shared__ int sh[1024];
    int v = (threadIdx.x < nb) ? bs[threadIdx.x] : 0;
    sh[threadIdx.x] = v; __syncthreads();
    for (int o = 1; o < 1024; o <<= 1) {
        int t = (threadIdx.x >= o) ? sh[threadIdx.x - o] : 0;
        __syncthreads();
        sh[threadIdx.x] += t;
        __syncthreads();
    }
    if (threadIdx.x < nb) bs[threadIdx.x] = sh[threadIdx.x] - v;
}
__global__ __launch_bounds__(256) void scan3_kernel(int* __restrict__ rp, int* __restrict__ cur,
                                                    const int* __restrict__ bs, int n, int E) {
    int i = blockIdx.x * 256 + threadIdx.x;
    if (i < n) {
        int v = rp[i] + bs[blockIdx.x];
        rp[i] = v;
        cur[i] = v;
    }
    if (i == 0) rp[n] = E;
}
__global__ __launch_bounds__(256) void fill_kernel(const int* __restrict__ src, const int* __restrict__ dst,
                                                   int* __restrict__ cur, int* __restrict__ srcs, int E, int Nn) {
    int e = blockIdx.x * 256 + threadIdx.x;
    if (e >= E) return;
    int d = dst[e];
    if ((unsigned)d >= (unsigned)Nn) return;
    int s = src[e];
    if ((unsigned)s >= (unsigned)Nn) s = 0;
    int p = atomicAdd(&cur[d], 1);
    srcs[p] = s;
}

// ================= CSR mean-aggregation -> bf16 m (4-way ILP) =================
template<bool L0>
__global__ __launch_bounds__(256) void agg_csr_kernel(const void* __restrict__ X, int ldx,
    const int* __restrict__ rp, const int* __restrict__ srcs,
    u16* __restrict__ m, int c0, int rows)
{
    int lrow = blockIdx.x * 4 + (threadIdx.x >> 6);
    if (lrow >= rows) return;
    int lane = threadIdx.x & 63;
    int r = c0 + lrow;
    int b = rp[r], e = rp[r + 1];
    float inv = 1.0f / fmaxf((float)(e - b), 1.0f);
    if (L0) {
        float a0 = 0.f, a1 = 0.f, b0 = 0.f, b1 = 0.f;
        float c0a = 0.f, c1a = 0.f, d0 = 0.f, d1 = 0.f;
        int i = b;
        for (; i + 4 <= e; i += 4) {
            int s0 = srcs[i], s1 = srcs[i + 1], s2 = srcs[i + 2], s3 = srcs[i + 3];
            float2 v0 = *(const float2*)((const float*)X + (long long)s0 * ldx + lane * 2);
            float2 v1 = *(const float2*)((const float*)X + (long long)s1 * ldx + lane * 2);
            float2 v2 = *(const float2*)((const float*)X + (long long)s2 * ldx + lane * 2);
            float2 v3 = *(const float2*)((const float*)X + (long long)s3 * ldx + lane * 2);
            a0 += v0.x; a1 += v0.y;
            b0 += v1.x; b1 += v1.y;
            c0a += v2.x; c1a += v2.y;
            d0 += v3.x; d1 += v3.y;
        }
        for (; i < e; ++i) {
            int s0 = srcs[i];
            float2 v0 = *(const float2*)((const float*)X + (long long)s0 * ldx + lane * 2);
            a0 += v0.x; a1 += v0.y;
        }
        a0 += b0 + c0a + d0; a1 += b1 + c1a + d1;
        ushort2 o; o.x = f2bf(a0 * inv); o.y = f2bf(a1 * inv);
        *(ushort2*)(m + (long long)lrow * 128 + lane * 2) = o;
    } else {
        float a0 = 0.f, a1 = 0.f, a2 = 0.f, a3 = 0.f;
        float b0 = 0.f, b1 = 0.f, b2 = 0.f, b3 = 0.f;
        float c0_ = 0.f, c1_ = 0.f, c2_ = 0.f, c3_ = 0.f;
        float d0 = 0.f, d1 = 0.f, d2 = 0.f, d3 = 0.f;
        int i = b;
        for (; i + 4 <= e; i += 4) {
            int s0 = srcs[i], s1 = srcs[i + 1], s2 = srcs[i + 2], s3 = srcs[i + 3];
            ushort4 u0 = *(const ushort4*)((const u16*)X + (long long)s0 * ldx + lane * 4);
            ushort4 u1 = *(const ushort4*)((const u16*)X + (long long)s1 * ldx + lane * 4);
            ushort4 u2 = *(const ushort4*)((const u16*)X + (long long)s2 * ldx + lane * 4);
            ushort4 u3 = *(const ushort4*)((const u16*)X + (long long)s3 * ldx + lane * 4);
            a0 += bf2f(u0.x); a1 += bf2f(u0.y); a2 += bf2f(u0.z); a3 += bf2f(u0.w);
            b0 += bf2f(u1.x); b1 += bf2f(u1.y); b2 += bf2f(u1.z); b3 += bf2f(u1.w);
            c0_ += bf2f(u2.x); c1_ += bf2f(u2.y); c2_ += bf2f(u2.z); c3_ += bf2f(u2.w);
            d0 += bf2f(u3.x); d1 += bf2f(u3.y); d2 += bf2f(u3.z); d3 += bf2f(u3.w);
        }
        for (; i < e; ++i) {
            int s0 = srcs[i];
            ushort4 u0 = *(const ushort4*)((const u16*)X + (long long)s0 * ldx + lane * 4);
            a0 += bf2f(u0.x); a1 += bf2f(u0.y); a2 += bf2f(u0.z); a3 += bf2f(u0.w);
        }
        a0 += b0 + c0_ + d0; a1 += b1 + c1_ + d1;
        a2 += b2 + c2_ + d2; a3 += b3 + c3_ + d3;
        ushort4 o;
        o.x = f2bf(a0 * inv); o.y = f2bf(a1 * inv); o.z = f2bf(a2 * inv); o.w = f2bf(a3 * inv);
        *(ushort4*)(m + (long long)lrow * 256 + lane * 4) = o;
    }
}

// ================= merged weight prep =================
struct PrepArgs {
    const float* W[11];
    short* outp[11];
    int K[11], Nc[11], kOff[11], Ktot[11];
    int start[12];
};
__global__ __launch_bounds__(256) void prep_all_kernel(PrepArgs a) {
    int idx = blockIdx.x * 256 + threadIdx.x;
    if (idx >= a.start[11]) return;
    int si = 0;
    #pragma unroll
    for (int j = 1; j < 11; ++j) si += (idx >= a.start[j]);
    int local = idx - a.start[si];
    int Nc = a.Nc[si];
    int k = local / Nc, n = local % Nc;
    a.outp[si][(long long)n * a.Ktot[si] + a.kOff[si] + k] = (short)f2bf(a.W[si][local]);
}

// ---------------- fp32 staging helper (reg path) ----------------
__device__ __forceinline__ void loadrow32(const float* p, short8v& o0, short8v& o1) {
    float4 a = *(const float4*)p;
    float4 b = *(const float4*)(p + 4);
    float4 c = *(const float4*)(p + 8);
    float4 d = *(const float4*)(p + 12);
    short8v r0, r1;
    r0[0] = (short)f2bf(a.x); r0[1] = (short)f2bf(a.y); r0[2] = (short)f2bf(a.z); r0[3] = (short)f2bf(a.w);
    r0[4] = (short)f2bf(b.x); r0[5] = (short)f2bf(b.y); r0[6] = (short)f2bf(b.z); r0[7] = (short)f2bf(b.w);
    r1[0] = (short)f2bf(c.x); r1[1] = (short)f2bf(c.y); r1[2] = (short)f2bf(c.z); r1[3] = (short)f2bf(c.w);
    r1[4] = (short)f2bf(d.x); r1[5] = (short)f2bf(d.y); r1[6] = (short)f2bf(d.z); r1[7] = (short)f2bf(d.w);
    o0 = r0; o1 = r1;
}

// ================= MFMA GEMM v3: async staging + chunk-XOR bank swizzle =================
template<int EPI, bool A1BF, bool A2BF, bool CBF, bool STAT, bool NORM>
__global__ __launch_bounds__(256) void mm_kernel(
    const void* __restrict__ A1, int lda1,
    const void* __restrict__ A2, int lda2,
    int K1, int K2,
    const short* __restrict__ Bhi, int ldb,
    const float* __restrict__ bias,
    const float* __restrict__ resid, int ldres,
    float* __restrict__ s1, float* __restrict__ s2,
    void* __restrict__ C, int ldc, int M)
{
    __shared__ short AsL[4096];      // [128][32] linear, chunk-swizzled content
    __shared__ short BhL[4096];
    __shared__ float cst[256];       // STAT: colsum[128] | colsq[128]
    __shared__ float rsq[128][2];    // NORM
    const int t = threadIdx.x;
    const int rowbase = blockIdx.y * 128;
    const int colbase = blockIdx.x * 128;
    const int lane = t & 63;
    const int wv = t >> 6;
    const int wr = (wv >> 1) << 6;
    const int wc = (wv & 1) << 6;
    const int l15 = lane & 15;
    const int rgrp = (lane >> 4) << 2;
    const int lr16 = lane >> 2;            // 0..15
    const int swz = (((lane & 3) ^ (lr16 & 3)) << 3);   // swizzled global elem offset
    const int ldsW = wv * 512;             // wave-uniform LDS elem base
    const int rdk = (((lane >> 4) ^ (l15 & 3)) << 3);   // read-side swizzled k offset
    if (STAT && t < 256) cst[t] = 0.f;
    f32x4 acc[4][4] = {};
    const int k1t = K1 >> 5;
    const int KT = (K1 + K2) >> 5;

    for (int kt = 0; kt < KT; ++kt) {
        const bool p1 = kt < k1t;
        const int kbl = (p1 ? kt : kt - k1t) << 5;
        {
            long long kb = (long long)(kt << 5) + swz;
            int r0 = colbase + wv * 16 + lr16;
            gll16(Bhi + (long long)r0 * ldb + kb, BhL + ldsW);
            gll16(Bhi + (long long)(r0 + 64) * ldb + kb, BhL + 2048 + ldsW);
        }
        if (p1 ? A1BF : A2BF) {
            const short* Ab = (const short*)(p1 ? A1 : A2);
            const int lda = p1 ? lda1 : lda2;
            int r0 = rowbase + wv * 16 + lr16;      if (r0 >= M) r0 = M - 1;
            int r1 = rowbase + 64 + wv * 16 + lr16; if (r1 >= M) r1 = M - 1;
            gll16(Ab + (long long)r0 * lda + kbl + swz, AsL + ldsW);
            gll16(Ab + (long long)r1 * lda + kbl + swz, AsL + 2048 + ldsW);
        } else {
            const float* Ab = (const float*)(p1 ? A1 : A2);
            const int lda = p1 ? lda1 : lda2;
            int row = t >> 1, h = (t & 1) << 1;
            int r = rowbase + row;
            short8v o0 = {0,0,0,0,0,0,0,0}, o1 = {0,0,0,0,0,0,0,0};
            if (r < M) loadrow32(Ab + (long long)r * lda + kbl + (h << 3), o0, o1);
            *(short8v*)&AsL[row * 32 + ((h ^ (row & 3)) << 3)]       = o0;
            *(short8v*)&AsL[row * 32 + (((h + 1) ^ (row & 3)) << 3)] = o1;
        }
        __syncthreads();
        short8v a4[4], b4[4];
        #pragma unroll
        for (int mr = 0; mr < 4; ++mr)
            a4[mr] = *(short8v*)&AsL[(wr + mr * 16 + l15) * 32 + rdk];
        #pragma unroll
        for (int nr = 0; nr < 4; ++nr)
            b4[nr] = *(short8v*)&BhL[(wc + nr * 16 + l15) * 32 + rdk];
        #pragma unroll
        for (int mr = 0; mr < 4; ++mr)
            #pragma unroll
            for (int nr = 0; nr < 4; ++nr)
                acc[mr][nr] = __builtin_amdgcn_mfma_f32_16x16x32_bf16(a4[mr], b4[nr], acc[mr][nr], 0, 0, 0);
        __syncthreads();
    }

    if (NORM) {
        float rs[4][4] = {};
        #pragma unroll
        for (int nr = 0; nr < 4; ++nr) {
            int c = colbase + wc + nr * 16 + l15;
            float bi = bias[c];
            #pragma unroll
            for (int mr = 0; mr < 4; ++mr)
                #pragma unroll
                for (int i = 0; i < 4; ++i) {
                    int r = rowbase + wr + mr * 16 + rgrp + i;
                    float v = 0.f;
                    if (r < M) {
                        v = acc[mr][nr][i] + bi;
                        if (EPI == 3) v += resid[(long long)r * ldres + c];
                        if (EPI == 1) v = geluf(v);
                    }
                    acc[mr][nr][i] = v;
                    rs[mr][i] += v * v;
                }
        }
        #pragma unroll
        for (int mr = 0; mr < 4; ++mr)
            #pragma unroll
            for (int i = 0; i < 4; ++i) {
                float s = rs[mr][i];
                s += __shfl_xor(s, 1); s += __shfl_xor(s, 2);
                s += __shfl_xor(s, 4); s += __shfl_xor(s, 8);
                rs[mr][i] = s;
            }
        if (l15 == 0) {
            #pragma unroll
            for (int mr = 0; mr < 4; ++mr)
                #pragma unroll
                for (int i = 0; i < 4; ++i)
                    rsq[wr + mr * 16 + rgrp + i][wv & 1] = rs[mr][i];
        }
        __syncthreads();
        #pragma unroll
        for (int mr = 0; mr < 4; ++mr)
            #pragma unroll
            for (int i = 0; i < 4; ++i) {
                int rl = wr + mr * 16 + rgrp + i;
                int r = rowbase + rl;
                if (r >= M) continue;
                float inv = 1.0f / (sqrtf(rsq[rl][0] + rsq[rl][1]) + 1e-10f);
                #pragma unroll
                for (int nr = 0; nr < 4; ++nr) {
                    int c = colbase + wc + nr * 16 + l15;
                    float v = acc[mr][nr][i] * inv;
                    if (CBF) ((u16*)C)[(long long)r * ldc + c] = f2bf(v);
                    else     ((float*)C)[(long long)r * ldc + c] = v;
                }
            }
    } else {
        #pragma unroll
        for (int nr = 0; nr < 4; ++nr) {
            int c = colbase + wc + nr * 16 + l15;
            float bi = bias[c];
            float cp = 0.f, cq = 0.f;
            #pragma unroll
            for (int mr = 0; mr < 4; ++mr)
                #pragma unroll
                for (int i = 0; i < 4; ++i) {
                    int r = rowbase + wr + mr * 16 + rgrp + i;
                    if (r >= M) continue;
                    float v = acc[mr][nr][i] + bi;
                    if (EPI == 1) v = geluf(v);
                    if (EPI == 3) v += resid[(long long)r * ldres + c];
                    if (CBF) ((u16*)C)[(long long)r * ldc + c] = f2bf(v);
                    else     ((float*)C)[(long long)r * ldc + c] = v;
                    if (STAT) { cp += v; cq += v * v; }
                }
            if (STAT) {
                cp += __shfl_xor(cp, 16); cp += __shfl_xor(cp, 32);
                cq += __shfl_xor(cq, 16); cq += __shfl_xor(cq, 32);
                if (lane < 16) {
                    int cl = wc + nr * 16 + l15;
                    atomicAdd(&cst[cl], cp);
                    atomicAdd(&cst[128 + cl], cq);
                }
            }
        }
        if (STAT) {
            __syncthreads();
            if (t < 128) {
                atomicAdd(s1 + colbase + t, cst[t]);
                atomicAdd(s2 + colbase + t, cst[128 + t]);
            }
        }
    }
}

// ================= pair kernel (64 pairs/block, 4 waves, hoisted A) =================
__global__ __launch_bounds__(256) void pair_kernel(
    const u16* __restrict__ zf,
    const int* __restrict__ g1, const int* __restrict__ g2,
    int Nn, int P,
    const short* __restrict__ C1t, const float* __restrict__ c1,
    const short* __restrict__ C2t, const float* __restrict__ c2,
    const float* __restrict__ C3, const float* __restrict__ c3,
    float* __restrict__ out)
{
    __shared__ short E1s[64 * 264];
    __shared__ float sc[64][2];
    const int t = threadIdx.x;
    const int lane = t & 63;
    const int wv = t >> 6;
    const int wr = (wv >> 1) << 5;   // 0 / 32
    const int wc = (wv & 1) << 6;    // 0 / 64
    const int l15 = lane & 15;
    const int kreg = (lane >> 4) << 3;
    const int rgrp = (lane >> 4) << 2;
    const int p0 = blockIdx.x * 64;

    int gidx[2][2];
    #pragma unroll
    for (int mr = 0; mr < 2; ++mr) {
        int pr = p0 + wr + mr * 16 + l15;
        int a = (pr < P) ? g1[pr] : 0;  if ((unsigned)a >= (unsigned)Nn) a = 0;
        gidx[0][mr] = a;
        int b = (pr < P) ? g2[pr] : 0;  if ((unsigned)b >= (unsigned)Nn) b = 0;
        gidx[1][mr] = b;
    }

    short8v az[2][2][4];   // [half][mr][ktl]
    #pragma unroll
    for (int half = 0; half < 2; ++half)
        #pragma unroll
        for (int mr = 0; mr < 2; ++mr)
            #pragma unroll
            for (int ktl = 0; ktl < 4; ++ktl)
                az[half][mr][ktl] = *(const short8v*)((const short*)zf
                    + (long long)gidx[half][mr] * 128 + (ktl << 5) + kreg);

    #pragma unroll
    for (int ch = 0; ch < 2; ++ch) {
        f32x4 acc1[2][4] = {};
        #pragma unroll
        for (int kt = 0; kt < 8; ++kt) {
            const int half = kt >> 2;
            const int ktl = kt & 3;
            short8v b4[4];
            #pragma unroll
            for (int nr = 0; nr < 4; ++nr)
                b4[nr] = *(const short8v*)(C1t + (long long)(ch * 128 + wc + nr * 16 + l15) * 256 + (kt << 5) + kreg);
            #pragma unroll
            for (int mr = 0; mr < 2; ++mr)
                #pragma unroll
                for (int nr = 0; nr < 4; ++nr)
                    acc1[mr][nr] = __builtin_amdgcn_mfma_f32_16x16x32_bf16(az[half][mr][ktl], b4[nr], acc1[mr][nr], 0, 0, 0);
        }
        #pragma unroll
        for (int nr = 0; nr < 4; ++nr) {
            int cc = wc + nr * 16 + l15;
            float bi = c1[ch * 128 + cc];
            #pragma unroll
            for (int mr = 0; mr < 2; ++mr)
                #pragma unroll
                for (int i = 0; i < 4; ++i) {
                    float v = geluf(acc1[mr][nr][i] + bi);
                    E1s[(wr + mr * 16 + rgrp + i) * 264 + ch * 128 + cc] = (short)f2bf(v);
                }
        }
    }
    __syncthreads();

    f32x4 acc[2][4] = {};
    #pragma unroll
    for (int kt = 0; kt < 8; ++kt) {
        short8v a4[2], b4[4];
        #pragma unroll
        for (int mr = 0; mr < 2; ++mr)
            a4[mr] = *(short8v*)&E1s[(wr + mr * 16 + l15) * 264 + (kt << 5) + kreg];
        #pragma unroll
        for (int nr = 0; nr < 4; ++nr)
            b4[nr] = *(const short8v*)(C2t + (long long)(wc + nr * 16 + l15) * 256 + (kt << 5) + kreg);
        #pragma unroll
        for (int mr = 0; mr < 2; ++mr)
            #pragma unroll
            for (int nr = 0; nr < 4; ++nr)
                acc[mr][nr] = __builtin_amdgcn_mfma_f32_16x16x32_bf16(a4[mr], b4[nr], acc[mr][nr], 0, 0, 0);
    }

    float pr_[2][4] = {};
    #pragma unroll
    for (int nr = 0; nr < 4; ++nr) {
        int cc = wc + nr * 16 + l15;
        float bi = c2[cc];
        float w3 = C3[cc];
        #pragma unroll
        for (int mr = 0; mr < 2; ++mr)
            #pragma unroll
            for (int i = 0; i < 4; ++i)
                pr_[mr][i] += geluf(acc[mr][nr][i] + bi) * w3;
    }
    #pragma unroll
    for (int mr = 0; mr < 2; ++mr)
        #pragma unroll
        for (int i = 0; i < 4; ++i) {
            float s = pr_[mr][i];
            s += __shfl_xor(s, 1); s += __shfl_xor(s, 2);
            s += __shfl_xor(s, 4); s += __shfl_xor(s, 8);
            pr_[mr][i] = s;
        }
    if (l15 == 0) {
        #pragma unroll
        for (int mr = 0; mr < 2; ++mr)
            #pragma unroll
            for (int i = 0; i < 4; ++i)
                sc[wr + mr * 16 + rgrp + i][wv & 1] = pr_[mr][i];
    }
    __syncthreads();
    if (t < 64) {
        int p = p0 + t;
        if (p < P) {
            float x = sc[t][0] + sc[t][1] + c3[0];
            out[p] = 1.0f / (1.0f + __expf(-x));
        }
    }
}

// ---------------- GraphNorm apply (+res), bf16 in place (layers 0,1) ----------------
__global__ __launch_bounds__(256) void gn_apply_kernel(u16* __restrict__ G, int ldg,
    const u16* __restrict__ prev, int ldp, int M,
    const float* __restrict__ s1, const float* __restrict__ s2,
    const float* __restrict__ gw, const float* __restrict__ gb, const float* __restrict__ gs,
    float invN)
{
    long long idx = (long long)blockIdx.x * blockDim.x + threadIdx.x;
    if (idx >= (long long)M * 64) return;
    int c0 = (int)(idx & 63) << 2;
    long long r = idx >> 6;
    float4 g = ld4<true>(G, r * ldg + c0);
    float o[4] = {g.x, g.y, g.z, g.w};
    #pragma unroll
    for (int j = 0; j < 4; ++j) {
        int c = c0 + j;
        float mu = s1[c] * invN;
        float ms = gs[c];
        float var = s2[c] * invN - mu * mu * ms * (2.0f - ms);
        float rstd = rsqrtf(var + 1e-5f);
        o[j] = (o[j] - ms * mu) * rstd * gw[c] + gb[c];
    }
    if (prev) {
        float4 pv = ld4<true>(prev, r * ldp + c0);
        o[0] += pv.x; o[1] += pv.y; o[2] += pv.z; o[3] += pv.w;
    }
    ushort4 u; u.x = f2bf(o[0]); u.y = f2bf(o[1]); u.z = f2bf(o[2]); u.w = f2bf(o[3]);
    *(ushort4*)((u16*)G + r * ldg + c0) = u;
}

// ---------------- layer-2 epilogue, fully fused (race-free pairing):
//   cols 0..255  (Z0): out = DyT(z)
//   cols 256..511 + 512..767 handled by ONE thread per quad-pair:
//     z1 = Z1 raw, z2 = Z2 raw
//     out1 = DyT(z1);  out2 = DyT(gn(z2) + z1)
__global__ __launch_bounds__(256) void gn_dyt_kernel(u16* __restrict__ Z, int M,
    const float* __restrict__ s1, const float* __restrict__ s2,
    const float* __restrict__ gw, const float* __restrict__ gb, const float* __restrict__ gs,
    float invN,
    const float* __restrict__ aP, const float* __restrict__ dW, const float* __restrict__ dB)
{
    long long idx = (long long)blockIdx.x * blockDim.x + threadIdx.x;
    if (idx >= (long long)M * 128) return;
    int cg = (int)(idx & 127);
    long long r = idx >> 7;
    float alpha = aP[0];
    if (cg < 64) {
        int c0 = cg << 2;
        ushort4 u = *(ushort4*)(Z + r * 768 + c0);
        float o0 = tanhfast(alpha * bf2f(u.x)) * dW[c0 + 0] + dB[c0 + 0];
        float o1 = tanhfast(alpha * bf2f(u.y)) * dW[c0 + 1] + dB[c0 + 1];
        float o2 = tanhfast(alpha * bf2f(u.z)) * dW[c0 + 2] + dB[c0 + 2];
        float o3 = tanhfast(alpha * bf2f(u.w)) * dW[c0 + 3] + dB[c0 + 3];
        ushort4 o; o.x = f2bf(o0); o.y = f2bf(o1); o.z = f2bf(o2); o.w = f2bf(o3);
        *(ushort4*)(Z + r * 768 + c0) = o;
    } else {
        int cl = (cg - 64) << 2;   // local col in [0,256)
        ushort4 u1 = *(ushort4*)(Z + r * 768 + 256 + cl);
        ushort4 u2 = *(ushort4*)(Z + r * 768 + 512 + cl);
        float z1[4] = {bf2f(u1.x), bf2f(u1.y), bf2f(u1.z), bf2f(u1.w)};
        float z2[4] = {bf2f(u2.x), bf2f(u2.y), bf2f(u2.z), bf2f(u2.w)};
        float o1[4], o2[4];
        #pragma unroll
        for (int j = 0; j < 4; ++j) {
            int c = cl + j;
            float mu = s1[c] * invN;
            float ms = gs[c];
            float var = s2[c] * invN - mu * mu * ms * (2.0f - ms);
            float rstd = rsqrtf(var + 1e-5f);
            float g2v = (z2[j] - ms * mu) * rstd * gw[c] + gb[c] + z1[j];
            o2[j] = tanhfast(alpha * g2v) * dW[512 + c] + dB[512 + c];
            o1[j] = tanhfast(alpha * z1[j]) * dW[256 + c] + dB[256 + c];
        }
        ushort4 w1, w2;
        w1.x = f2bf(o1[0]); w1.y = f2bf(o1[1]); w1.z = f2bf(o1[2]); w1.w = f2bf(o1[3]);
        w2.x = f2bf(o2[0]); w2.y = f2bf(o2[1]); w2.z = f2bf(o2[2]); w2.w = f2bf(o2[3]);
        *(ushort4*)(Z + r * 768 + 256 + cl) = w1;
        *(ushort4*)(Z + r * 768 + 512 + cl) = w2;
    }
}

extern "C" void kernel_launch(void* const* d_in, const int* in_sizes, int n_in,
                              void* d_out, int out_size, void* d_ws, size_t ws_size,
                              hipStream_t stream) {
    const float* x_res = (const float*)d_in[0];
    const int* eidx = (const int*)d_in[1];
    const int* cidx = (const int*)d_in[2];
    const int N = in_sizes[0] / 128;
    const int E = in_sizes[1] / 2;
    const int P = in_sizes[2] / 2;
    const int* src = eidx;
    const int* dst = eidx + E;
    const int* g1 = cidx;
    const int* g2 = cidx + P;
    const float* Wl[3] = {(const float*)d_in[3], (const float*)d_in[9],  (const float*)d_in[15]};
    const float* Wr[3] = {(const float*)d_in[4], (const float*)d_in[10], (const float*)d_in[16]};
    const float* bc[3] = {(const float*)d_in[5], (const float*)d_in[11], (const float*)d_in[17]};
    const float* gnw[3] = {(const float*)d_in[6], (const float*)d_in[12], (const float*)d_in[18]};
    const float* gnb[3] = {(const float*)d_in[7], (const float*)d_in[13], (const float*)d_in[19]};
    const float* gns[3] = {(const float*)d_in[8], (const float*)d_in[14], (const float*)d_in[20]};
    const float* alphaP = (const float*)d_in[21];
    const float* dytw = (const float*)d_in[22];
    const float* dytb = (const float*)d_in[23];
    const float* W1 = (const float*)d_in[24]; const float* b1 = (const float*)d_in[25];
    const float* W2 = (const float*)d_in[26]; const float* b2 = (const float*)d_in[27];
    const float* W3 = (const float*)d_in[28]; const float* b3 = (const float*)d_in[29];
    const float* C1 = (const float*)d_in[30]; const float* c1 = (const float*)d_in[31];
    const float* C2 = (const float*)d_in[32]; const float* c2 = (const float*)d_in[33];
    const float* C3 = (const float*)d_in[34]; const float* c3 = (const float*)d_in[35];
    float* out = (float*)d_out;

    // ---- workspace layout ----
    char* ws = (char*)d_ws;
    size_t off = 0;
    size_t zOff  = off; off += (size_t)N * 768 * 2;     off = (off + 255) & ~(size_t)255;
    size_t stOff = off; off += 4096;                    off = (off + 255) & ~(size_t)255;
    size_t zfOff = off; off += (size_t)N * 128 * 2;     off = (off + 255) & ~(size_t)255;
    size_t rpOff = off; off += (size_t)(N + 1) * 4;     off = (off + 255) & ~(size_t)255;
    size_t curOff = off; off += (size_t)N * 4;          off = (off + 255) & ~(size_t)255;
    size_t srcsOff = off; off += (size_t)E * 4;         off = (off + 255) & ~(size_t)255;
    size_t bsOff = off; off += 4096;                    off = (off + 255) & ~(size_t)255;
    static const size_t se[8] = {65536, 131072, 131072, 393216, 262144, 65536, 65536, 32768};
    short* wt[8];
    for (int i = 0; i < 8; ++i) {
        wt[i] = (short*)(ws + off);
        off += 2 * se[i];
        off = (off + 255) & ~(size_t)255;
    }
    size_t pOff = off;
    size_t avail = ws_size > pOff ? ws_size - pOff : 0;

    u16*   Z    = (u16*)(ws + zOff);
    float* st   = (float*)(ws + stOff);
    u16*   zf   = (u16*)(ws + zfOff);
    int*   rp   = (int*)(ws + rpOff);
    int*   cur  = (int*)(ws + curOff);
    int*   srcs = (int*)(ws + srcsOff);
    int*   bs   = (int*)(ws + bsOff);
    u16*   pbuf = (u16*)(ws + pOff);

    int NC = (int)((avail /  512) & ~(size_t)127); if (NC < 128) NC = 128; if (NC > N) NC = N; // m: 256 bf16/row
    int S  = (int)((avail / 2048) & ~(size_t)127); if (S  < 128) S  = 128; if (S  > N) S  = N; // t1+t2 bf16

    dim3 blk(256);

    // ---- merged weight prep ----
    {
        PrepArgs a;
        const float* Ws[11] = {Wl[0], Wr[0], Wl[1], Wr[1], Wl[2], Wr[2], W1, W2, W3, C1, C2};
        short* Os[11] = {wt[0], wt[0], wt[1], wt[1], wt[2], wt[2], wt[3], wt[4], wt[5], wt[6], wt[7]};
        int Ks[11]    = {128, 128, 256, 256, 256, 256, 768, 512, 512, 256, 256};
        int Ncs[11]   = {256, 256, 256, 256, 256, 256, 512, 512, 128, 256, 128};
        int kOffs[11] = {0, 128, 0, 256, 0, 256, 0, 0, 0, 0, 0};
        int Ktots[11] = {256, 256, 512, 512, 512, 512, 768, 512, 512, 256, 256};
        int s = 0;
        for (int i = 0; i < 11; ++i) {
            a.W[i] = Ws[i]; a.outp[i] = Os[i];
            a.K[i] = Ks[i]; a.Nc[i] = Ncs[i]; a.kOff[i] = kOffs[i]; a.Ktot[i] = Ktots[i];
            a.start[i] = s;
            s += Ks[i] * Ncs[i];
        }
        a.start[11] = s;
        prep_all_kernel<<<(s + 255) / 256, 256, 0, stream>>>(a);
    }

    // ---- CSR build ----
    int nb = (N + 255) / 256;
    hipMemsetAsync(cur, 0, (size_t)N * 4, stream);
    cnt_kernel<<<(E + 255) / 256, 256, 0, stream>>>(dst, cur, E, N);
    scan1_kernel<<<nb, 256, 0, stream>>>(cur, rp, bs, N);
    scan2_kernel<<<1, 1024, 0, stream>>>(bs, nb);
    scan3_kernel<<<nb, 256, 0, stream>>>(rp, cur, bs, N, E);
    fill_kernel<<<(E + 255) / 256, 256, 0, stream>>>(src, dst, cur, srcs, E, N);

    // ---- 3 SAGE + GELU(+stats) + GraphNorm (+res; l2: fully fused gn+res+DyT x3) ----
    u16* m = pbuf;
    for (int l = 0; l < 3; ++l) {
        u16* Zl = Z + l * 256;
        hipMemsetAsync(st, 0, 512 * 4, stream);
        for (int c0 = 0; c0 < N; c0 += NC) {
            int rows = (N - c0 < NC) ? (N - c0) : NC;
            int aggblocks = (rows + 3) / 4;
            dim3 grid(2, (rows + 127) / 128);
            if (l == 0) {
                agg_csr_kernel<true><<<aggblocks, 256, 0, stream>>>(x_res, 128, rp, srcs, m, c0, rows);
                mm_kernel<1, true, false, true, true, false><<<grid, blk, 0, stream>>>(
                    m, 128, x_res + (size_t)c0 * 128, 128, 128, 128,
                    wt[0], 256, bc[0], nullptr, 0, st, st + 256,
                    Zl + (size_t)c0 * 768, 768, rows);
            } else {
                const u16* h = Z + (l - 1) * 256;
                agg_csr_kernel<false><<<aggblocks, 256, 0, stream>>>(h, 768, rp, srcs, m, c0, rows);
                mm_kernel<1, true, true, true, true, false><<<grid, blk, 0, stream>>>(
                    m, 256, h + (size_t)c0 * 768, 768, 256, 256,
                    wt[l], 512, bc[l], nullptr, 0, st, st + 256,
                    Zl + (size_t)c0 * 768, 768, rows);
            }
        }
        if (l < 2) {
            const u16* prev = (l == 0) ? nullptr : (Z + (l - 1) * 256);
            int gnblocks = (int)(((long long)N * 64 + 255) / 256);
            gn_apply_kernel<<<gnblocks, 256, 0, stream>>>(
                Zl, 768, prev, 768, N, st, st + 256, gnw[l], gnb[l], gns[l], 1.0f / (float)N);
        } else {
            // fused layer-2 gn+residual+DyT over ALL 768 cols (race-free z1/z2 pairing)
            int gblocks = (int)(((long long)N * 128 + 255) / 256);
            gn_dyt_kernel<<<gblocks, 256, 0, stream>>>(
                Z, N, st, st + 256, gnw[2], gnb[2], gns[2], 1.0f / (float)N,
                alphaP, dytw, dytb);
        }
    }

    // ---- node MLP, chunked (t1/t2 bf16 in scratch); W3 fuses residual + row-L2-norm ----
    {
        short* t1c = (short*)pbuf;
        short* t2c = t1c + (size_t)S * 512;
        for (int r0 = 0; r0 < N; r0 += S) {
            int rows = (N - r0 < S) ? (N - r0) : S;
            mm_kernel<1, true, true, true, false, false><<<dim3(4, (rows + 127) / 128), blk, 0, stream>>>(
                Z + (size_t)r0 * 768, 768, nullptr, 0, 768, 0,
                wt[3], 768, b1, nullptr, 0, nullptr, nullptr, t1c, 512, rows);
            mm_kernel<1, true, true, true, false, false><<<dim3(4, (rows + 127) / 128), blk, 0, stream>>>(
                t1c, 512, nullptr, 0, 512, 0,
                wt[4], 512, b2, nullptr, 0, nullptr, nullptr, t2c, 512, rows);
            mm_kernel<3, true, true, true, false, true><<<dim3(1, (rows + 127) / 128), blk, 0, stream>>>(
                t2c, 512, nullptr, 0, 512, 0,
                wt[5], 512, b3, x_res + (size_t)r0 * 128, 128, nullptr, nullptr,
                zf + (size_t)r0 * 128, 128, rows);
        }
    }

    // ---- fused pair scoring: e1 (from L3-resident zf) + e2 + score ----
    pair_kernel<<<(P + 63) / 64, blk, 0, stream>>>(
        zf, g1, g2, N, P, wt[6], c1, wt[7], c2, C3, c3, out);
}